// Round 8
// baseline (912.222 us; speedup 1.0000x reference)
//
#include <hip/hip_runtime.h>
#include <hip/hip_bf16.h>

#define NN 50000
#define NE 800000
#define NG 64
#define SCAN_B 196   // 196*256 = 50176 >= NN
#define NBUCK 250
#define BN 200       // nodes per bucket; NBUCK*BN == NN
#define SMAX 6144    // staged csr segment capacity (ints)

__device__ __forceinline__ float bf2f(unsigned short u){
    unsigned v = ((unsigned)u) << 16; float f; __builtin_memcpy(&f, &v, 4); return f;
}
__device__ __forceinline__ unsigned short f2bf(float f){
    unsigned u; __builtin_memcpy(&u, &f, 4);
    u = (u + 0x7fffu + ((u >> 16) & 1u)) >> 16;
    return (unsigned short)u;
}
__device__ __forceinline__ float lrelu(float v){ return v > 0.f ? v : 0.2f * v; }

__device__ __forceinline__ float ldflex(const void* p, long i, int isbf){
    if (isbf) return bf2f(((const unsigned short*)p)[i]);
    return ((const float*)p)[i];
}
__device__ __forceinline__ int ldidx(const int* p, long i, int is64){
    return p[is64 ? (i << 1) : i];
}

// ---- fp8 e4m3fn (OCP) pack/unpack, HW cvt when available ----
__device__ __forceinline__ unsigned int enc_fp8_1(float f){
    unsigned u; __builtin_memcpy(&u, &f, 4);
    unsigned s = (u >> 24) & 0x80u;
    float a = fabsf(f); a = fminf(a, 448.f);
    float x = a * 0x1p-120f;
    unsigned xu; __builtin_memcpy(&xu, &x, 4);
    unsigned r = (xu + 0x7FFFFu + ((xu >> 20) & 1u)) >> 20;
    if (r > 0x7Eu) r = 0x7Eu;
    return s | r;
}
__device__ __forceinline__ unsigned short pk_fp8(float a, float b){
#if __has_builtin(__builtin_amdgcn_cvt_pk_fp8_f32)
    int r = __builtin_amdgcn_cvt_pk_fp8_f32(a, b, 0, false);
    return (unsigned short)(r & 0xFFFF);
#else
    return (unsigned short)(enc_fp8_1(a) | (enc_fp8_1(b) << 8));
#endif
}
__device__ __forceinline__ float dec_fp8_manual(unsigned int byte){
    unsigned bits = ((byte & 0x80u) << 24) | ((byte & 0x7Fu) << 20);
    float f; __builtin_memcpy(&f, &bits, 4);
    return f * 0x1p120f;
}
__device__ __forceinline__ void dec_fp8x4(unsigned int v, float* o){
#if __has_builtin(__builtin_amdgcn_cvt_f32_fp8)
    o[0] = __builtin_amdgcn_cvt_f32_fp8((int)v, 0);
    o[1] = __builtin_amdgcn_cvt_f32_fp8((int)v, 1);
    o[2] = __builtin_amdgcn_cvt_f32_fp8((int)v, 2);
    o[3] = __builtin_amdgcn_cvt_f32_fp8((int)v, 3);
#else
    o[0] = dec_fp8_manual(v & 0xFF);
    o[1] = dec_fp8_manual((v >> 8) & 0xFF);
    o[2] = dec_fp8_manual((v >> 16) & 0xFF);
    o[3] = dec_fp8_manual((v >> 24) & 0xFF);
#endif
}

__device__ __forceinline__ int rdlane_i(int v, int l){ return __builtin_amdgcn_readlane(v, l); }
__device__ __forceinline__ float rdlane_f(float v, int l){
    int i; __builtin_memcpy(&i, &v, 4);
    int r = __builtin_amdgcn_readlane(i, l);
    float f; __builtin_memcpy(&f, &r, 4);
    return f;
}

// ---------------- runtime dtype detection ----------------
__global__ void detect_kernel(const unsigned short* xu, const unsigned int* eiu,
                              const unsigned int* bu, int* flags){
    if (threadIdx.x != 0 || blockIdx.x != 0) return;
    int hit = 0;
    for (int i = 0; i < 128; i++){
        int ex = (xu[2 * i] >> 7) & 0xFF;
        if (ex >= 100 && ex <= 140) hit++;
    }
    flags[0] = (hit >= 64) ? 1 : 0;
    int z = 0;
    for (int i = 0; i < 128; i++) if (eiu[2 * i + 1] == 0) z++;
    flags[1] = (z >= 120) ? 1 : 0;
    z = 0;
    for (int i = 0; i < 128; i++) if (bu[49745 + 2 * i] == 0) z++;
    flags[2] = (z >= 120) ? 1 : 0;
}

// ---------------- CSR build ----------------
__global__ void count_kernel(const int* __restrict__ ei, int* __restrict__ counts,
                             const int* __restrict__ flags){
    int f64 = flags[1];
    int e = blockIdx.x * 256 + threadIdx.x;
    if (e < NE) atomicAdd(&counts[ldidx(ei, (long)NE + e, f64)], 1);
}

__global__ __launch_bounds__(256) void scan_part(const int* __restrict__ counts,
                                                 int* __restrict__ bsum){
    __shared__ int red[256];
    int tid = threadIdx.x;
    int i = blockIdx.x * 256 + tid;
    red[tid] = (i < NN) ? counts[i] : 0;
    __syncthreads();
    for (int s = 128; s > 0; s >>= 1){
        if (tid < s) red[tid] += red[tid + s];
        __syncthreads();
    }
    if (tid == 0) bsum[blockIdx.x] = red[0];
}

__global__ __launch_bounds__(256) void scan_mid(int* __restrict__ bsum){
    __shared__ int sd[256];
    int tid = threadIdx.x;
    int v = (tid < SCAN_B) ? bsum[tid] : 0;
    sd[tid] = v; __syncthreads();
    for (int off = 1; off < 256; off <<= 1){
        int x = sd[tid];
        int y = (tid >= off) ? sd[tid - off] : 0;
        __syncthreads();
        sd[tid] = x + y;
        __syncthreads();
    }
    if (tid < SCAN_B) bsum[tid] = sd[tid] - v;  // exclusive
}

__global__ __launch_bounds__(256) void scan_final(const int* __restrict__ counts,
                                                  const int* __restrict__ bsum,
                                                  int* __restrict__ row_ptr,
                                                  int* __restrict__ bcur){
    __shared__ int sd[256];
    int tid = threadIdx.x;
    int i = blockIdx.x * 256 + tid;
    int v = (i < NN) ? counts[i] : 0;
    sd[tid] = v; __syncthreads();
    for (int off = 1; off < 256; off <<= 1){
        int x = sd[tid];
        int y = (tid >= off) ? sd[tid - off] : 0;
        __syncthreads();
        sd[tid] = x + y;
        __syncthreads();
    }
    if (i < NN){
        int excl = sd[tid] - v + bsum[blockIdx.x];
        row_ptr[i] = excl;
        if (i % BN == 0) bcur[i / BN] = excl;   // bucket append cursors
    }
    if (i == 0) row_ptr[NN] = NE;
}

// phase 1: bucket edges by dst/BN; bucket writes are sequential -> full lines
__global__ void bucket_kernel(const int* __restrict__ ei,
                              int* __restrict__ bcur, int2* __restrict__ ebuf,
                              const int* __restrict__ flags){
    int f64 = flags[1];
    int e = blockIdx.x * 256 + threadIdx.x;
    if (e < NE){
        int d = ldidx(ei, (long)NE + e, f64);
        int s = ldidx(ei, (long)e, f64);
        int b = d / BN;
        int pos = atomicAdd(&bcur[b], 1);
        ebuf[pos] = make_int2(s, d);
    }
}

// phase 2: one block per bucket; LDS-staged csr segment, contiguous dump
__global__ __launch_bounds__(256) void place_kernel(const int2* __restrict__ ebuf,
                                                    const int* __restrict__ row_ptr,
                                                    int* __restrict__ csr){
    __shared__ int lcur[BN];
    __shared__ int stage[SMAX];
    int k = blockIdx.x, tid = threadIdx.x;
    int n0 = k * BN;
    int seg0 = row_ptr[n0], seg1 = row_ptr[n0 + BN];
    int len = seg1 - seg0;
    for (int i = tid; i < BN; i += 256)
        lcur[i] = row_ptr[n0 + i] - seg0;
    __syncthreads();
    if (len <= SMAX){
        for (int j = tid; j < len; j += 256){
            int2 e = ebuf[seg0 + j];
            int p = atomicAdd(&lcur[e.y - n0], 1);
            stage[p] = e.x;
        }
        __syncthreads();
        for (int j = tid; j < len; j += 256)
            csr[seg0 + j] = stage[j];
    } else {
        for (int j = tid; j < len; j += 256){
            int2 e = ebuf[seg0 + j];
            int p = atomicAdd(&lcur[e.y - n0], 1);
            csr[seg0 + p] = e.x;
        }
    }
}

// ---------------- fused GEMM + es/ed epilogue, fp8-packed h output -------
// hq rows: 96 fp8 channels padded to 128 B stride (32 dwords).
template<int K, int H>
__global__ __launch_bounds__(256) void gemm_es_kernel(const void* __restrict__ in_,
                                                      const void* __restrict__ Wg,
                                                      const void* __restrict__ as_,
                                                      const void* __restrict__ ad_,
                                                      unsigned short* __restrict__ hq16,
                                                      float* __restrict__ es,
                                                      float* __restrict__ ed,
                                                      const int* __restrict__ flags,
                                                      int in_flex){
    constexpr int KC = 32;
    __shared__ float xs[KC][68];
    __shared__ float ws[KC][96];
    int isbf = flags[0];
    int inbf = in_flex ? isbf : 0;
    int tid = threadIdx.x;
    int row0 = blockIdx.x * 64;
    int tx = tid & 15, ty = tid >> 4;     // cols tx*6..+5, rows ty*4..+3
    float acc[4][6] = {};

    for (int k0 = 0; k0 < K; k0 += KC){
        {
            int r = tid >> 2, kb = (tid & 3) * 8;
            int rr = row0 + r; if (rr >= NN) rr = NN - 1;
            long base = (long)rr * K + k0 + kb;
            #pragma unroll
            for (int i = 0; i < 8; i++)
                xs[kb + i][r] = ldflex(in_, base + i, inbf);
        }
        for (int i = tid; i < KC * 96; i += 256){
            int kk = i / 96, cc = i - kk * 96;
            ws[kk][cc] = ldflex(Wg, (long)(k0 + kk) * 96 + cc, isbf);
        }
        __syncthreads();
        #pragma unroll 4
        for (int k = 0; k < KC; k++){
            float xr[4], wr[6];
            #pragma unroll
            for (int i = 0; i < 4; i++) xr[i] = xs[k][ty * 4 + i];
            #pragma unroll
            for (int j = 0; j < 6; j++) wr[j] = ws[k][tx * 6 + j];
            #pragma unroll
            for (int i = 0; i < 4; i++)
                #pragma unroll
                for (int j = 0; j < 6; j++)
                    acc[i][j] += xr[i] * wr[j];
        }
        __syncthreads();
    }

    float pes[4] = {}, ped[4] = {};
    #pragma unroll
    for (int j = 0; j < 6; j++){
        int c = tx * 6 + j;
        float av = ldflex(as_, c, isbf);
        float dv = ldflex(ad_, c, isbf);
        #pragma unroll
        for (int i = 0; i < 4; i++){ pes[i] += acc[i][j] * av; ped[i] += acc[i][j] * dv; }
    }
    constexpr int G = (H == 2) ? 8 : 16;
    for (int off = 1; off < G; off <<= 1){
        #pragma unroll
        for (int i = 0; i < 4; i++){
            pes[i] += __shfl_xor(pes[i], off);
            ped[i] += __shfl_xor(ped[i], off);
        }
    }
    #pragma unroll
    for (int i = 0; i < 4; i++){
        int r = row0 + ty * 4 + i;
        if (r < NN){
            long o = (long)r * 64 + tx * 3;   // short index, 64 shorts per 128B row
            hq16[o + 0] = pk_fp8(acc[i][0], acc[i][1]);
            hq16[o + 1] = pk_fp8(acc[i][2], acc[i][3]);
            hq16[o + 2] = pk_fp8(acc[i][4], acc[i][5]);
            if ((tx & (G - 1)) == 0){
                int hd = tx / G;
                es[(long)r * H + hd] = pes[i];
                ed[(long)r * H + hd] = ped[i];
            }
        }
    }
}

// ---------------- attention: wave per node, fp8 rows, 2 edges/step --------
// lanes 48-63: metadata (csr + es gather + exp) one 16-edge batch ahead.
// lanes 0-23: even edges, lanes 24-47: odd edges; each lane 1 dword = 4 ch.
template<int H>
__global__ __launch_bounds__(256) void attn_kernel(const unsigned int* __restrict__ hq,
                                                   const float* __restrict__ es,
                                                   const float* __restrict__ ed,
                                                   const int* __restrict__ row_ptr,
                                                   const int* __restrict__ csr,
                                                   const void* __restrict__ bias,
                                                   float* __restrict__ out,
                                                   const int* __restrict__ flags){
    int lane = threadIdx.x & 63;
    int d = blockIdx.x * 4 + (threadIdx.x >> 6);
    if (d >= NN) return;
    int isbf = flags[0];
    int beg = row_ptr[d], deg = row_ptr[d + 1] - beg;
    float edd0 = ed[(long)d * H];
    float edd1 = (H == 2) ? ed[(long)d * H + 1] : edd0;
    int g = (lane >= 24 && lane < 48) ? 1 : 0;
    int c = lane - g * 24;                  // dword index 0..23 for gather lanes
    bool head0 = (c < 12);                  // channels 4c..4c+3 -> head = c/12
    int m = lane - 48;

    // prefetch batch 0 metadata (lanes 48-63)
    int s_nxt = 0; float p0_nxt = 0.f, p1_nxt = 0.f;
    if (lane >= 48 && m < deg){
        int sj = csr[beg + m];
        s_nxt = sj;
        p0_nxt = __expf(lrelu(es[(long)sj * H] + edd0));
        if (H == 2) p1_nxt = __expf(lrelu(es[(long)sj * H + 1] + edd1));
    }

    float acc[4] = {0.f, 0.f, 0.f, 0.f};
    float dn0 = 0.f, dn1 = 0.f;            // metadata lanes accumulate
    for (int base = 0; base < deg; base += 16){
        int s_cur = s_nxt; float p0c = p0_nxt, p1c = p1_nxt;
        dn0 += p0c; dn1 += p1c;            // nonzero only on metadata lanes
        int nb = base + 16;
        s_nxt = 0; p0_nxt = 0.f; p1_nxt = 0.f;
        if (lane >= 48 && nb + m < deg){
            int sj = csr[beg + nb + m];
            s_nxt = sj;
            p0_nxt = __expf(lrelu(es[(long)sj * H] + edd0));
            if (H == 2) p1_nxt = __expf(lrelu(es[(long)sj * H + 1] + edd1));
        }
        unsigned int v[8]; float pv[8];
        #pragma unroll
        for (int jj = 0; jj < 8; jj++){
            int sa = rdlane_i(s_cur, 48 + 2 * jj);
            int sb = rdlane_i(s_cur, 49 + 2 * jj);
            int s = g ? sb : sa;
            float pa0 = rdlane_f(p0c, 48 + 2 * jj);
            float pb0 = rdlane_f(p0c, 49 + 2 * jj);
            float p;
            if (H == 2){
                float pa1 = rdlane_f(p1c, 48 + 2 * jj);
                float pb1 = rdlane_f(p1c, 49 + 2 * jj);
                float pa = head0 ? pa0 : pa1;
                float pb = head0 ? pb0 : pb1;
                p = g ? pb : pa;
            } else {
                p = g ? pb0 : pa0;
            }
            pv[jj] = p;
            v[jj] = (lane < 48) ? hq[(unsigned)s * 32u + (unsigned)c] : 0u;
        }
        #pragma unroll
        for (int jj = 0; jj < 8; jj++){
            float f[4];
            dec_fp8x4(v[jj], f);
            float p = pv[jj];
            acc[0] += p * f[0]; acc[1] += p * f[1];
            acc[2] += p * f[2]; acc[3] += p * f[3];
        }
    }

    // reduce dn across the 16 metadata lanes
    for (int off = 1; off < 16; off <<= 1){
        dn0 += __shfl_xor(dn0, off);
        if (H == 2) dn1 += __shfl_xor(dn1, off);
    }
    float dn0_t = rdlane_f(dn0, 48);
    float dn1_t = (H == 2) ? rdlane_f(dn1, 48) : dn0_t;

    // combine the two edge groups: lane c<24 takes partner lane c+24
    float tot[4];
    #pragma unroll
    for (int k = 0; k < 4; k++) tot[k] = acc[k] + __shfl(acc[k], lane + 24);

    if (lane < 24){
        float ps0 = __expf(lrelu(es[(long)d * H] + edd0));
        float ps1 = (H == 2) ? __expf(lrelu(es[(long)d * H + 1] + edd1)) : ps0;
        float ps = head0 ? ps0 : ps1;
        float dn = (head0 ? dn0_t : dn1_t) + ps;
        float f[4];
        dec_fp8x4(hq[(unsigned)d * 32u + (unsigned)c], f);
        float4 o;
        o.x = fmaxf((tot[0] + ps * f[0]) / dn + ldflex(bias, 4 * c + 0, isbf), 0.f);
        o.y = fmaxf((tot[1] + ps * f[1]) / dn + ldflex(bias, 4 * c + 1, isbf), 0.f);
        o.z = fmaxf((tot[2] + ps * f[2]) / dn + ldflex(bias, 4 * c + 2, isbf), 0.f);
        o.w = fmaxf((tot[3] + ps * f[3]) / dn + ldflex(bias, 4 * c + 3, isbf), 0.f);
        ((float4*)out)[(long)d * 24 + c] = o;
    }
}

// ---------------- pooling ----------------
__global__ __launch_bounds__(128) void pool_kernel(const float* __restrict__ in,
                                                   const int* __restrict__ batch,
                                                   float* __restrict__ pooled,
                                                   int* __restrict__ gcnt,
                                                   const int* __restrict__ flags){
    int f64 = flags[2];
    int n0 = blockIdx.x * 128;
    if (n0 >= NN) return;
    int n1 = n0 + 128; if (n1 > NN) n1 = NN;
    int tid = threadIdx.x;
    if (tid < 96){
        int c = tid;
        float acc = 0.f;
        int curg = ldidx(batch, n0, f64);
        for (int nd = n0; nd < n1; nd++){
            int g = ldidx(batch, nd, f64);
            if (g != curg){
                atomicAdd(&pooled[curg * 96 + c], acc);
                acc = 0.f; curg = g;
            }
            acc += in[(long)nd * 96 + c];
        }
        atomicAdd(&pooled[curg * 96 + c], acc);
    } else if (tid == 96){
        int cnt = 0;
        int curg = ldidx(batch, n0, f64);
        for (int nd = n0; nd < n1; nd++){
            int g = ldidx(batch, nd, f64);
            if (g != curg){
                atomicAdd(&gcnt[curg], cnt);
                cnt = 0; curg = g;
            }
            cnt++;
        }
        atomicAdd(&gcnt[curg], cnt);
    }
}

__global__ void final_kernel(const float* __restrict__ pooled, const int* __restrict__ gcnt,
                             const void* __restrict__ Wc, const void* __restrict__ bc,
                             void* __restrict__ outp, const int* __restrict__ flags){
    int isbf = flags[0];
    int g = threadIdx.x;
    if (g >= NG) return;
    float cnt = (float)gcnt[g];
    if (cnt < 1.f) cnt = 1.f;
    float acc = 0.f;
    for (int c = 0; c < 96; c++)
        acc += (pooled[g * 96 + c] / cnt) * ldflex(Wc, c, isbf);
    acc += ldflex(bc, 0, isbf);
    float sg = 1.f / (1.f + __expf(-acc));
    if (isbf) ((unsigned short*)outp)[g] = f2bf(sg);
    else      ((float*)outp)[g] = sg;
}

extern "C" void kernel_launch(void* const* d_in, const int* in_sizes, int n_in,
                              void* d_out, int out_size, void* d_ws, size_t ws_size,
                              hipStream_t stream){
    const void* x     = d_in[0];
    const int* ei     = (const int*)d_in[1];
    const int* batch  = (const int*)d_in[3];
    const void* W[4]  = {d_in[4],  d_in[8],  d_in[12], d_in[16]};
    const void* AS[4] = {d_in[5],  d_in[9],  d_in[13], d_in[17]};
    const void* AD[4] = {d_in[6],  d_in[10], d_in[14], d_in[18]};
    const void* B[4]  = {d_in[7],  d_in[11], d_in[15], d_in[19]};
    const void* Wc    = d_in[20];
    const void* bc    = d_in[21];

    char* p = (char*)d_ws;
    auto alloc = [&](size_t bytes) -> void* {
        void* r = (void*)p;
        p += (bytes + 255) & ~(size_t)255;
        return r;
    };
    int* flags     = (int*)alloc(16);
    unsigned int* hq = (unsigned int*)alloc((size_t)NN * 128);   // fp8 rows, 128B stride
    float* buf1    = (float*)alloc((size_t)NN * 96 * 4);         // attn out (f32)
    float* es      = (float*)alloc((size_t)NN * 2 * 4);
    float* ed      = (float*)alloc((size_t)NN * 2 * 4);
    int* counts    = (int*)alloc((size_t)NN * 4);
    int* row_ptr   = (int*)alloc((size_t)(NN + 1) * 4);
    int* csr       = (int*)alloc((size_t)NE * 4);
    int2* ebuf     = (int2*)alloc((size_t)NE * 8);
    int* bcur      = (int*)alloc((size_t)NBUCK * 4);
    int* bsum      = (int*)alloc((size_t)SCAN_B * 4);
    float* pooled  = (float*)alloc((size_t)NG * 96 * 4);
    int* gcnt      = (int*)alloc((size_t)NG * 4);

    detect_kernel<<<1, 64, 0, stream>>>((const unsigned short*)x, (const unsigned int*)ei,
                                        (const unsigned int*)batch, flags);

    // CSR build (by dst): count -> scan -> bucket (sequential writes) -> place
    hipMemsetAsync(counts, 0, (size_t)NN * 4, stream);
    count_kernel<<<(NE + 255) / 256, 256, 0, stream>>>(ei, counts, flags);
    scan_part<<<SCAN_B, 256, 0, stream>>>(counts, bsum);
    scan_mid<<<1, 256, 0, stream>>>(bsum);
    scan_final<<<SCAN_B, 256, 0, stream>>>(counts, bsum, row_ptr, bcur);
    bucket_kernel<<<(NE + 255) / 256, 256, 0, stream>>>(ei, bcur, ebuf, flags);
    place_kernel<<<NBUCK, 256, 0, stream>>>(ebuf, row_ptr, csr);

    const int GB = (NN + 63) / 64;        // 782
    const int AB = (NN + 3) / 4;          // 12500

    // layer 1 (H=2, K=128, input may be bf16-flex)
    gemm_es_kernel<128, 2><<<GB, 256, 0, stream>>>(x, W[0], AS[0], AD[0],
                                                   (unsigned short*)hq, es, ed, flags, 1);
    attn_kernel<2><<<AB, 256, 0, stream>>>(hq, es, ed, row_ptr, csr, B[0], buf1, flags);
    // layers 2..4 (H=1, K=96)
    for (int l = 1; l < 4; l++){
        gemm_es_kernel<96, 1><<<GB, 256, 0, stream>>>(buf1, W[l], AS[l], AD[l],
                                                      (unsigned short*)hq, es, ed, flags, 0);
        attn_kernel<1><<<AB, 256, 0, stream>>>(hq, es, ed, row_ptr, csr, B[l], buf1, flags);
    }

    hipMemsetAsync(pooled, 0, (size_t)NG * 96 * 4, stream);
    hipMemsetAsync(gcnt, 0, (size_t)NG * 4, stream);
    pool_kernel<<<(NN + 127) / 128, 128, 0, stream>>>(buf1, batch, pooled, gcnt, flags);
    final_kernel<<<1, 64, 0, stream>>>(pooled, gcnt, Wc, bc, d_out, flags);
}

// Round 9
// 517.509 us; speedup vs baseline: 1.7627x; 1.7627x over previous
//
#include <hip/hip_runtime.h>
#include <hip/hip_bf16.h>

#define NN 50000
#define NE 800000
#define NG 64
#define NBUCK 256
#define BN 196        // nodes per bucket; 256*196 = 50176 >= NN
#define EPB 4096      // edges per binning block
#define HB 196        // ceil(NE/EPB)
#define SMAX 4200     // per-bucket segment capacity (mean 3136, sigma 56)

__device__ __forceinline__ float bf2f(unsigned short u){
    unsigned v = ((unsigned)u) << 16; float f; __builtin_memcpy(&f, &v, 4); return f;
}
__device__ __forceinline__ unsigned short f2bf(float f){
    unsigned u; __builtin_memcpy(&u, &f, 4);
    u = (u + 0x7fffu + ((u >> 16) & 1u)) >> 16;
    return (unsigned short)u;
}
__device__ __forceinline__ float lrelu(float v){ return v > 0.f ? v : 0.2f * v; }

__device__ __forceinline__ float ldflex(const void* p, long i, int isbf){
    if (isbf) return bf2f(((const unsigned short*)p)[i]);
    return ((const float*)p)[i];
}
__device__ __forceinline__ int ldidx(const int* p, long i, int is64){
    return p[is64 ? (i << 1) : i];
}

// ---- fp8 e4m3fn (OCP) pack/unpack, HW cvt when available ----
__device__ __forceinline__ unsigned int enc_fp8_1(float f){
    unsigned u; __builtin_memcpy(&u, &f, 4);
    unsigned s = (u >> 24) & 0x80u;
    float a = fabsf(f); a = fminf(a, 448.f);
    float x = a * 0x1p-120f;
    unsigned xu; __builtin_memcpy(&xu, &x, 4);
    unsigned r = (xu + 0x7FFFFu + ((xu >> 20) & 1u)) >> 20;
    if (r > 0x7Eu) r = 0x7Eu;
    return s | r;
}
__device__ __forceinline__ unsigned short pk_fp8(float a, float b){
#if __has_builtin(__builtin_amdgcn_cvt_pk_fp8_f32)
    int r = __builtin_amdgcn_cvt_pk_fp8_f32(a, b, 0, false);
    return (unsigned short)(r & 0xFFFF);
#else
    return (unsigned short)(enc_fp8_1(a) | (enc_fp8_1(b) << 8));
#endif
}
__device__ __forceinline__ float dec_fp8_manual(unsigned int byte){
    unsigned bits = ((byte & 0x80u) << 24) | ((byte & 0x7Fu) << 20);
    float f; __builtin_memcpy(&f, &bits, 4);
    return f * 0x1p120f;
}
__device__ __forceinline__ void dec_fp8x4(unsigned int v, float* o){
#if __has_builtin(__builtin_amdgcn_cvt_f32_fp8)
    o[0] = __builtin_amdgcn_cvt_f32_fp8((int)v, 0);
    o[1] = __builtin_amdgcn_cvt_f32_fp8((int)v, 1);
    o[2] = __builtin_amdgcn_cvt_f32_fp8((int)v, 2);
    o[3] = __builtin_amdgcn_cvt_f32_fp8((int)v, 3);
#else
    o[0] = dec_fp8_manual(v & 0xFF);
    o[1] = dec_fp8_manual((v >> 8) & 0xFF);
    o[2] = dec_fp8_manual((v >> 16) & 0xFF);
    o[3] = dec_fp8_manual((v >> 24) & 0xFF);
#endif
}

__device__ __forceinline__ int rdlane_i(int v, int l){ return __builtin_amdgcn_readlane(v, l); }
__device__ __forceinline__ float rdlane_f(float v, int l){
    int i; __builtin_memcpy(&i, &v, 4);
    int r = __builtin_amdgcn_readlane(i, l);
    float f; __builtin_memcpy(&f, &r, 4);
    return f;
}

// ---------------- runtime dtype detection ----------------
__global__ void detect_kernel(const unsigned short* xu, const unsigned int* eiu,
                              const unsigned int* bu, int* flags){
    if (threadIdx.x != 0 || blockIdx.x != 0) return;
    int hit = 0;
    for (int i = 0; i < 128; i++){
        int ex = (xu[2 * i] >> 7) & 0xFF;
        if (ex >= 100 && ex <= 140) hit++;
    }
    flags[0] = (hit >= 64) ? 1 : 0;
    int z = 0;
    for (int i = 0; i < 128; i++) if (eiu[2 * i + 1] == 0) z++;
    flags[1] = (z >= 120) ? 1 : 0;
    z = 0;
    for (int i = 0; i < 128; i++) if (bu[49745 + 2 * i] == 0) z++;
    flags[2] = (z >= 120) ? 1 : 0;
}

// ---------------- CSR build: block-aggregated bucket sort ----------------
// 1) per-block LDS histogram of bucket ids -> global bucket counts
__global__ __launch_bounds__(256) void bhist_kernel(const int* __restrict__ ei,
                                                    int* __restrict__ bcnt,
                                                    const int* __restrict__ flags){
    __shared__ int h[NBUCK];
    int tid = threadIdx.x;
    h[tid] = 0; __syncthreads();
    int f64 = flags[1];
    long e0 = (long)blockIdx.x * EPB + tid;
    #pragma unroll
    for (int r = 0; r < 16; r++){
        long e = e0 + r * 256;
        if (e < NE){
            int d = ldidx(ei, NE + e, f64);
            atomicAdd(&h[d / BN], 1);
        }
    }
    __syncthreads();
    atomicAdd(&bcnt[tid], h[tid]);
}

// 2) scan bucket counts -> bases + cursors
__global__ __launch_bounds__(256) void bscan_kernel(const int* __restrict__ bcnt,
                                                    int* __restrict__ bbase,
                                                    int* __restrict__ bcur){
    __shared__ int sd[NBUCK];
    int tid = threadIdx.x;
    int v = bcnt[tid];
    sd[tid] = v; __syncthreads();
    for (int off = 1; off < 256; off <<= 1){
        int x = sd[tid];
        int y = (tid >= off) ? sd[tid - off] : 0;
        __syncthreads();
        sd[tid] = x + y;
        __syncthreads();
    }
    int excl = sd[tid] - v;
    bbase[tid] = excl;
    bcur[tid] = excl;
    if (tid == 255) bbase[256] = excl + v;   // == NE
}

// 3) block-staged scatter into bucket-sorted ebuf (contiguous runs -> full lines)
__global__ __launch_bounds__(256) void bscatter_kernel(const int* __restrict__ ei,
                                                       int* __restrict__ bcur,
                                                       int2* __restrict__ ebuf,
                                                       const int* __restrict__ flags){
    __shared__ int h[NBUCK], lofs[NBUCK], gbase[NBUCK], lcur[NBUCK];
    __shared__ int2 lstage[EPB];
    int tid = threadIdx.x;
    int f64 = flags[1];
    h[tid] = 0; __syncthreads();
    int2 ed[16]; int bk[16];
    long e0 = (long)blockIdx.x * EPB + tid;
    #pragma unroll
    for (int r = 0; r < 16; r++){
        long e = e0 + r * 256;
        if (e < NE){
            int s = ldidx(ei, e, f64);
            int d = ldidx(ei, NE + e, f64);
            ed[r] = make_int2(s, d);
            bk[r] = d / BN;
            atomicAdd(&h[bk[r]], 1);
        } else bk[r] = -1;
    }
    __syncthreads();
    int v = h[tid];
    lofs[tid] = v; __syncthreads();
    for (int off = 1; off < 256; off <<= 1){
        int x = lofs[tid];
        int y = (tid >= off) ? lofs[tid - off] : 0;
        __syncthreads();
        lofs[tid] = x + y;
        __syncthreads();
    }
    int excl = lofs[tid] - v;
    lofs[tid] = excl;
    lcur[tid] = excl;
    if (v > 0) gbase[tid] = atomicAdd(&bcur[tid], v);
    __syncthreads();
    #pragma unroll
    for (int r = 0; r < 16; r++){
        if (bk[r] >= 0){
            int p = atomicAdd(&lcur[bk[r]], 1);
            lstage[p] = ed[r];
        }
    }
    __syncthreads();
    long base = (long)blockIdx.x * EPB;
    int cnt = (NE - base < EPB) ? (int)(NE - base) : EPB;
    for (int j = tid; j < cnt; j += 256){
        int2 e = lstage[j];
        int i = e.y / BN;
        ebuf[gbase[i] + j - lofs[i]] = e;
    }
}

// 4) per-bucket: node-level row_ptr + ordered csr dump
__global__ __launch_bounds__(256) void place_kernel(const int2* __restrict__ ebuf,
                                                    const int* __restrict__ bbase,
                                                    int* __restrict__ row_ptr,
                                                    int* __restrict__ csr){
    __shared__ int nh[BN];
    __shared__ int nofs[256];
    __shared__ int lcur[BN];
    __shared__ int stage[SMAX];
    int k = blockIdx.x, tid = threadIdx.x;
    int n0 = k * BN;
    int seg0 = bbase[k], len = bbase[k + 1] - seg0;
    for (int i = tid; i < BN; i += 256) nh[i] = 0;
    __syncthreads();
    for (int j = tid; j < len; j += 256){
        int2 e = ebuf[seg0 + j];
        atomicAdd(&nh[e.y - n0], 1);
    }
    __syncthreads();
    int v = (tid < BN) ? nh[tid] : 0;
    nofs[tid] = v; __syncthreads();
    for (int off = 1; off < 256; off <<= 1){
        int x = nofs[tid];
        int y = (tid >= off) ? nofs[tid - off] : 0;
        __syncthreads();
        nofs[tid] = x + y;
        __syncthreads();
    }
    int excl = nofs[tid] - v;
    if (tid < BN){
        lcur[tid] = excl;
        int node = n0 + tid;
        if (node < NN) row_ptr[node] = seg0 + excl;
    }
    if (k == NBUCK - 1 && tid == 0) row_ptr[NN] = NE;
    __syncthreads();
    if (len <= SMAX){
        for (int j = tid; j < len; j += 256){
            int2 e = ebuf[seg0 + j];
            int p = atomicAdd(&lcur[e.y - n0], 1);
            stage[p] = e.x;
        }
        __syncthreads();
        for (int j = tid; j < len; j += 256)
            csr[seg0 + j] = stage[j];
    } else {
        for (int j = tid; j < len; j += 256){
            int2 e = ebuf[seg0 + j];
            int p = atomicAdd(&lcur[e.y - n0], 1);
            csr[seg0 + p] = e.x;
        }
    }
}

// ---------------- fused GEMM + es/ed epilogue, fp8-packed h output -------
// hq rows: 96 fp8 channels padded to 128 B stride (32 dwords).
template<int K, int H>
__global__ __launch_bounds__(256) void gemm_es_kernel(const void* __restrict__ in_,
                                                      const void* __restrict__ Wg,
                                                      const void* __restrict__ as_,
                                                      const void* __restrict__ ad_,
                                                      unsigned short* __restrict__ hq16,
                                                      float* __restrict__ es,
                                                      float* __restrict__ ed,
                                                      const int* __restrict__ flags,
                                                      int in_flex){
    constexpr int KC = 32;
    __shared__ float xs[KC][68];
    __shared__ float ws[KC][96];
    int isbf = flags[0];
    int inbf = in_flex ? isbf : 0;
    int tid = threadIdx.x;
    int row0 = blockIdx.x * 64;
    int tx = tid & 15, ty = tid >> 4;     // cols tx*6..+5, rows ty*4..+3
    float acc[4][6] = {};

    for (int k0 = 0; k0 < K; k0 += KC){
        {
            int r = tid >> 2, kb = (tid & 3) * 8;
            int rr = row0 + r; if (rr >= NN) rr = NN - 1;
            long base = (long)rr * K + k0 + kb;
            #pragma unroll
            for (int i = 0; i < 8; i++)
                xs[kb + i][r] = ldflex(in_, base + i, inbf);
        }
        for (int i = tid; i < KC * 96; i += 256){
            int kk = i / 96, cc = i - kk * 96;
            ws[kk][cc] = ldflex(Wg, (long)(k0 + kk) * 96 + cc, isbf);
        }
        __syncthreads();
        #pragma unroll 4
        for (int k = 0; k < KC; k++){
            float xr[4], wr[6];
            #pragma unroll
            for (int i = 0; i < 4; i++) xr[i] = xs[k][ty * 4 + i];
            #pragma unroll
            for (int j = 0; j < 6; j++) wr[j] = ws[k][tx * 6 + j];
            #pragma unroll
            for (int i = 0; i < 4; i++)
                #pragma unroll
                for (int j = 0; j < 6; j++)
                    acc[i][j] += xr[i] * wr[j];
        }
        __syncthreads();
    }

    float pes[4] = {}, ped[4] = {};
    #pragma unroll
    for (int j = 0; j < 6; j++){
        int c = tx * 6 + j;
        float av = ldflex(as_, c, isbf);
        float dv = ldflex(ad_, c, isbf);
        #pragma unroll
        for (int i = 0; i < 4; i++){ pes[i] += acc[i][j] * av; ped[i] += acc[i][j] * dv; }
    }
    constexpr int G = (H == 2) ? 8 : 16;
    for (int off = 1; off < G; off <<= 1){
        #pragma unroll
        for (int i = 0; i < 4; i++){
            pes[i] += __shfl_xor(pes[i], off);
            ped[i] += __shfl_xor(ped[i], off);
        }
    }
    #pragma unroll
    for (int i = 0; i < 4; i++){
        int r = row0 + ty * 4 + i;
        if (r < NN){
            long o = (long)r * 64 + tx * 3;   // short index, 64 shorts per 128B row
            hq16[o + 0] = pk_fp8(acc[i][0], acc[i][1]);
            hq16[o + 1] = pk_fp8(acc[i][2], acc[i][3]);
            hq16[o + 2] = pk_fp8(acc[i][4], acc[i][5]);
            if ((tx & (G - 1)) == 0){
                int hd = tx / G;
                es[(long)r * H + hd] = pes[i];
                ed[(long)r * H + hd] = ped[i];
            }
        }
    }
}

// ---------------- attention: wave per node, fp8 rows, 2 edges/step --------
// lanes 48-63: metadata (csr + es gather + exp) one 16-edge batch ahead.
// lanes 0-23: even edges, lanes 24-47: odd edges; each lane 1 dword = 4 ch.
template<int H>
__global__ __launch_bounds__(256) void attn_kernel(const unsigned int* __restrict__ hq,
                                                   const float* __restrict__ es,
                                                   const float* __restrict__ ed,
                                                   const int* __restrict__ row_ptr,
                                                   const int* __restrict__ csr,
                                                   const void* __restrict__ bias,
                                                   float* __restrict__ out,
                                                   const int* __restrict__ flags){
    int lane = threadIdx.x & 63;
    int d = blockIdx.x * 4 + (threadIdx.x >> 6);
    if (d >= NN) return;
    int isbf = flags[0];
    int beg = row_ptr[d], deg = row_ptr[d + 1] - beg;
    float edd0 = ed[(long)d * H];
    float edd1 = (H == 2) ? ed[(long)d * H + 1] : edd0;
    int g = (lane >= 24 && lane < 48) ? 1 : 0;
    int c = lane - g * 24;                  // dword index 0..23 for gather lanes
    bool head0 = (c < 12);                  // channels 4c..4c+3 -> head = c/12
    int m = lane - 48;

    // prefetch batch 0 metadata (lanes 48-63)
    int s_nxt = 0; float p0_nxt = 0.f, p1_nxt = 0.f;
    if (lane >= 48 && m < deg){
        int sj = csr[beg + m];
        s_nxt = sj;
        p0_nxt = __expf(lrelu(es[(long)sj * H] + edd0));
        if (H == 2) p1_nxt = __expf(lrelu(es[(long)sj * H + 1] + edd1));
    }

    float acc[4] = {0.f, 0.f, 0.f, 0.f};
    float dn0 = 0.f, dn1 = 0.f;            // metadata lanes accumulate
    for (int base = 0; base < deg; base += 16){
        int s_cur = s_nxt; float p0c = p0_nxt, p1c = p1_nxt;
        dn0 += p0c; dn1 += p1c;            // nonzero only on metadata lanes
        int nb = base + 16;
        s_nxt = 0; p0_nxt = 0.f; p1_nxt = 0.f;
        if (lane >= 48 && nb + m < deg){
            int sj = csr[beg + nb + m];
            s_nxt = sj;
            p0_nxt = __expf(lrelu(es[(long)sj * H] + edd0));
            if (H == 2) p1_nxt = __expf(lrelu(es[(long)sj * H + 1] + edd1));
        }
        unsigned int v[8]; float pv[8];
        #pragma unroll
        for (int jj = 0; jj < 8; jj++){
            int sa = rdlane_i(s_cur, 48 + 2 * jj);
            int sb = rdlane_i(s_cur, 49 + 2 * jj);
            int s = g ? sb : sa;
            float pa0 = rdlane_f(p0c, 48 + 2 * jj);
            float pb0 = rdlane_f(p0c, 49 + 2 * jj);
            float p;
            if (H == 2){
                float pa1 = rdlane_f(p1c, 48 + 2 * jj);
                float pb1 = rdlane_f(p1c, 49 + 2 * jj);
                float pa = head0 ? pa0 : pa1;
                float pb = head0 ? pb0 : pb1;
                p = g ? pb : pa;
            } else {
                p = g ? pb0 : pa0;
            }
            pv[jj] = p;
            v[jj] = (lane < 48) ? hq[(unsigned)s * 32u + (unsigned)c] : 0u;
        }
        #pragma unroll
        for (int jj = 0; jj < 8; jj++){
            float f[4];
            dec_fp8x4(v[jj], f);
            float p = pv[jj];
            acc[0] += p * f[0]; acc[1] += p * f[1];
            acc[2] += p * f[2]; acc[3] += p * f[3];
        }
    }

    // reduce dn across the 16 metadata lanes
    for (int off = 1; off < 16; off <<= 1){
        dn0 += __shfl_xor(dn0, off);
        if (H == 2) dn1 += __shfl_xor(dn1, off);
    }
    float dn0_t = rdlane_f(dn0, 48);
    float dn1_t = (H == 2) ? rdlane_f(dn1, 48) : dn0_t;

    // combine the two edge groups: lane c<24 takes partner lane c+24
    float tot[4];
    #pragma unroll
    for (int k = 0; k < 4; k++) tot[k] = acc[k] + __shfl(acc[k], lane + 24);

    if (lane < 24){
        float ps0 = __expf(lrelu(es[(long)d * H] + edd0));
        float ps1 = (H == 2) ? __expf(lrelu(es[(long)d * H + 1] + edd1)) : ps0;
        float ps = head0 ? ps0 : ps1;
        float dn = (head0 ? dn0_t : dn1_t) + ps;
        float f[4];
        dec_fp8x4(hq[(unsigned)d * 32u + (unsigned)c], f);
        float4 o;
        o.x = fmaxf((tot[0] + ps * f[0]) / dn + ldflex(bias, 4 * c + 0, isbf), 0.f);
        o.y = fmaxf((tot[1] + ps * f[1]) / dn + ldflex(bias, 4 * c + 1, isbf), 0.f);
        o.z = fmaxf((tot[2] + ps * f[2]) / dn + ldflex(bias, 4 * c + 2, isbf), 0.f);
        o.w = fmaxf((tot[3] + ps * f[3]) / dn + ldflex(bias, 4 * c + 3, isbf), 0.f);
        ((float4*)out)[(long)d * 24 + c] = o;
    }
}

// ---------------- pooling ----------------
__global__ __launch_bounds__(128) void pool_kernel(const float* __restrict__ in,
                                                   const int* __restrict__ batch,
                                                   float* __restrict__ pooled,
                                                   int* __restrict__ gcnt,
                                                   const int* __restrict__ flags){
    int f64 = flags[2];
    int n0 = blockIdx.x * 128;
    if (n0 >= NN) return;
    int n1 = n0 + 128; if (n1 > NN) n1 = NN;
    int tid = threadIdx.x;
    if (tid < 96){
        int c = tid;
        float acc = 0.f;
        int curg = ldidx(batch, n0, f64);
        for (int nd = n0; nd < n1; nd++){
            int g = ldidx(batch, nd, f64);
            if (g != curg){
                atomicAdd(&pooled[curg * 96 + c], acc);
                acc = 0.f; curg = g;
            }
            acc += in[(long)nd * 96 + c];
        }
        atomicAdd(&pooled[curg * 96 + c], acc);
    } else if (tid == 96){
        int cnt = 0;
        int curg = ldidx(batch, n0, f64);
        for (int nd = n0; nd < n1; nd++){
            int g = ldidx(batch, nd, f64);
            if (g != curg){
                atomicAdd(&gcnt[curg], cnt);
                cnt = 0; curg = g;
            }
            cnt++;
        }
        atomicAdd(&gcnt[curg], cnt);
    }
}

__global__ void final_kernel(const float* __restrict__ pooled, const int* __restrict__ gcnt,
                             const void* __restrict__ Wc, const void* __restrict__ bc,
                             void* __restrict__ outp, const int* __restrict__ flags){
    int isbf = flags[0];
    int g = threadIdx.x;
    if (g >= NG) return;
    float cnt = (float)gcnt[g];
    if (cnt < 1.f) cnt = 1.f;
    float acc = 0.f;
    for (int c = 0; c < 96; c++)
        acc += (pooled[g * 96 + c] / cnt) * ldflex(Wc, c, isbf);
    acc += ldflex(bc, 0, isbf);
    float sg = 1.f / (1.f + __expf(-acc));
    if (isbf) ((unsigned short*)outp)[g] = f2bf(sg);
    else      ((float*)outp)[g] = sg;
}

extern "C" void kernel_launch(void* const* d_in, const int* in_sizes, int n_in,
                              void* d_out, int out_size, void* d_ws, size_t ws_size,
                              hipStream_t stream){
    const void* x     = d_in[0];
    const int* ei     = (const int*)d_in[1];
    const int* batch  = (const int*)d_in[3];
    const void* W[4]  = {d_in[4],  d_in[8],  d_in[12], d_in[16]};
    const void* AS[4] = {d_in[5],  d_in[9],  d_in[13], d_in[17]};
    const void* AD[4] = {d_in[6],  d_in[10], d_in[14], d_in[18]};
    const void* B[4]  = {d_in[7],  d_in[11], d_in[15], d_in[19]};
    const void* Wc    = d_in[20];
    const void* bc    = d_in[21];

    char* p = (char*)d_ws;
    auto alloc = [&](size_t bytes) -> void* {
        void* r = (void*)p;
        p += (bytes + 255) & ~(size_t)255;
        return r;
    };
    int* flags     = (int*)alloc(16);
    unsigned int* hq = (unsigned int*)alloc((size_t)NN * 128);   // fp8 rows, 128B stride
    float* buf1    = (float*)alloc((size_t)NN * 96 * 4);         // attn out (f32)
    float* es      = (float*)alloc((size_t)NN * 2 * 4);
    float* ed      = (float*)alloc((size_t)NN * 2 * 4);
    int* row_ptr   = (int*)alloc((size_t)(NN + 1) * 4);
    int* csr       = (int*)alloc((size_t)NE * 4);
    int2* ebuf     = (int2*)alloc((size_t)NE * 8);
    int* bcnt      = (int*)alloc((size_t)NBUCK * 4);
    int* bbase     = (int*)alloc((size_t)(NBUCK + 1) * 4);
    int* bcur      = (int*)alloc((size_t)NBUCK * 4);
    float* pooled  = (float*)alloc((size_t)NG * 96 * 4);
    int* gcnt      = (int*)alloc((size_t)NG * 4);

    detect_kernel<<<1, 64, 0, stream>>>((const unsigned short*)x, (const unsigned int*)ei,
                                        (const unsigned int*)batch, flags);

    // CSR build: LDS-aggregated bucket sort (no high-contention atomics,
    // no random 4B global writes)
    hipMemsetAsync(bcnt, 0, (size_t)NBUCK * 4, stream);
    bhist_kernel<<<HB, 256, 0, stream>>>(ei, bcnt, flags);
    bscan_kernel<<<1, 256, 0, stream>>>(bcnt, bbase, bcur);
    bscatter_kernel<<<HB, 256, 0, stream>>>(ei, bcur, ebuf, flags);
    place_kernel<<<NBUCK, 256, 0, stream>>>(ebuf, bbase, row_ptr, csr);

    const int GB = (NN + 63) / 64;        // 782
    const int AB = (NN + 3) / 4;          // 12500

    // layer 1 (H=2, K=128, input may be bf16-flex)
    gemm_es_kernel<128, 2><<<GB, 256, 0, stream>>>(x, W[0], AS[0], AD[0],
                                                   (unsigned short*)hq, es, ed, flags, 1);
    attn_kernel<2><<<AB, 256, 0, stream>>>(hq, es, ed, row_ptr, csr, B[0], buf1, flags);
    // layers 2..4 (H=1, K=96)
    for (int l = 1; l < 4; l++){
        gemm_es_kernel<96, 1><<<GB, 256, 0, stream>>>(buf1, W[l], AS[l], AD[l],
                                                      (unsigned short*)hq, es, ed, flags, 0);
        attn_kernel<1><<<AB, 256, 0, stream>>>(hq, es, ed, row_ptr, csr, B[l], buf1, flags);
    }

    hipMemsetAsync(pooled, 0, (size_t)NG * 96 * 4, stream);
    hipMemsetAsync(gcnt, 0, (size_t)NG * 4, stream);
    pool_kernel<<<(NN + 127) / 128, 128, 0, stream>>>(buf1, batch, pooled, gcnt, flags);
    final_kernel<<<1, 64, 0, stream>>>(pooled, gcnt, Wc, bc, d_out, flags);
}

// Round 10
// 450.331 us; speedup vs baseline: 2.0257x; 1.1492x over previous
//
#include <hip/hip_runtime.h>
#include <hip/hip_bf16.h>

#define NN 50000
#define NE 800000
#define NG 64
#define NBUCK 256
#define BN 196        // nodes per bucket; 256*196 = 50176 >= NN
#define EPB 4096      // edges per binning block
#define HB 196        // ceil(NE/EPB)
#define SMAX 4200     // per-bucket segment capacity (mean 3136, sigma 56)

typedef __attribute__((ext_vector_type(8))) short short8;
typedef __attribute__((ext_vector_type(4))) float float4v;

__device__ __forceinline__ float bf2f(unsigned short u){
    unsigned v = ((unsigned)u) << 16; float f; __builtin_memcpy(&f, &v, 4); return f;
}
__device__ __forceinline__ unsigned short f2bf(float f){
    unsigned u; __builtin_memcpy(&u, &f, 4);
    u = (u + 0x7fffu + ((u >> 16) & 1u)) >> 16;
    return (unsigned short)u;
}
__device__ __forceinline__ float lrelu(float v){ return v > 0.f ? v : 0.2f * v; }

__device__ __forceinline__ float ldflex(const void* p, long i, int isbf){
    if (isbf) return bf2f(((const unsigned short*)p)[i]);
    return ((const float*)p)[i];
}
__device__ __forceinline__ int ldidx(const int* p, long i, int is64){
    return p[is64 ? (i << 1) : i];
}

// ---- fp8 e4m3fn (OCP) pack/unpack, HW cvt when available ----
__device__ __forceinline__ unsigned int enc_fp8_1(float f){
    unsigned u; __builtin_memcpy(&u, &f, 4);
    unsigned s = (u >> 24) & 0x80u;
    float a = fabsf(f); a = fminf(a, 448.f);
    float x = a * 0x1p-120f;
    unsigned xu; __builtin_memcpy(&xu, &x, 4);
    unsigned r = (xu + 0x7FFFFu + ((xu >> 20) & 1u)) >> 20;
    if (r > 0x7Eu) r = 0x7Eu;
    return s | r;
}
__device__ __forceinline__ unsigned short pk_fp8(float a, float b){
#if __has_builtin(__builtin_amdgcn_cvt_pk_fp8_f32)
    int r = __builtin_amdgcn_cvt_pk_fp8_f32(a, b, 0, false);
    return (unsigned short)(r & 0xFFFF);
#else
    return (unsigned short)(enc_fp8_1(a) | (enc_fp8_1(b) << 8));
#endif
}
__device__ __forceinline__ float dec_fp8_manual(unsigned int byte){
    unsigned bits = ((byte & 0x80u) << 24) | ((byte & 0x7Fu) << 20);
    float f; __builtin_memcpy(&f, &bits, 4);
    return f * 0x1p120f;
}
__device__ __forceinline__ void dec_fp8x4(unsigned int v, float* o){
#if __has_builtin(__builtin_amdgcn_cvt_f32_fp8)
    o[0] = __builtin_amdgcn_cvt_f32_fp8((int)v, 0);
    o[1] = __builtin_amdgcn_cvt_f32_fp8((int)v, 1);
    o[2] = __builtin_amdgcn_cvt_f32_fp8((int)v, 2);
    o[3] = __builtin_amdgcn_cvt_f32_fp8((int)v, 3);
#else
    o[0] = dec_fp8_manual(v & 0xFF);
    o[1] = dec_fp8_manual((v >> 8) & 0xFF);
    o[2] = dec_fp8_manual((v >> 16) & 0xFF);
    o[3] = dec_fp8_manual((v >> 24) & 0xFF);
#endif
}

__device__ __forceinline__ int rdlane_i(int v, int l){ return __builtin_amdgcn_readlane(v, l); }
__device__ __forceinline__ float rdlane_f(float v, int l){
    int i; __builtin_memcpy(&i, &v, 4);
    int r = __builtin_amdgcn_readlane(i, l);
    float f; __builtin_memcpy(&f, &r, 4);
    return f;
}

// ---------------- runtime dtype detection ----------------
__global__ void detect_kernel(const unsigned short* xu, const unsigned int* eiu,
                              const unsigned int* bu, int* flags){
    if (threadIdx.x != 0 || blockIdx.x != 0) return;
    int hit = 0;
    for (int i = 0; i < 128; i++){
        int ex = (xu[2 * i] >> 7) & 0xFF;
        if (ex >= 100 && ex <= 140) hit++;
    }
    flags[0] = (hit >= 64) ? 1 : 0;
    int z = 0;
    for (int i = 0; i < 128; i++) if (eiu[2 * i + 1] == 0) z++;
    flags[1] = (z >= 120) ? 1 : 0;
    z = 0;
    for (int i = 0; i < 128; i++) if (bu[49745 + 2 * i] == 0) z++;
    flags[2] = (z >= 120) ? 1 : 0;
}

// ---------------- weight transpose + bf16 prep (4 blocks, one per layer) ---
__global__ __launch_bounds__(256) void wtprep_kernel(const void* W0, const void* W1,
                                                     const void* W2, const void* W3,
                                                     unsigned short* wt_all,
                                                     const int* flags){
    int l = blockIdx.x;
    const void* W = (l == 0) ? W0 : (l == 1) ? W1 : (l == 2) ? W2 : W3;
    int K = (l == 0) ? 128 : 96;
    unsigned short* out = wt_all + ((l == 0) ? 0 : (96 * 128 + (l - 1) * 96 * 96));
    int isbf = flags[0];
    int tot = 96 * K;
    for (int i = threadIdx.x; i < tot; i += 256){
        int c = i / K, k = i - c * K;
        out[i] = f2bf(ldflex(W, (long)k * 96 + c, isbf));
    }
}

// ---------------- x -> bf16 conversion (layer 1 input) ----------------
__global__ __launch_bounds__(256) void xconv_kernel(const void* x, unsigned short* xb,
                                                    const int* flags){
    int isbf = flags[0];
    long i8 = ((long)blockIdx.x * 256 + threadIdx.x) * 8;
    if (i8 >= (long)NN * 128) return;
    unsigned int o[4];
    #pragma unroll
    for (int j = 0; j < 4; j++){
        unsigned short a = f2bf(ldflex(x, i8 + 2 * j, isbf));
        unsigned short b = f2bf(ldflex(x, i8 + 2 * j + 1, isbf));
        o[j] = (unsigned)a | ((unsigned)b << 16);
    }
    *(uint4*)(xb + i8) = make_uint4(o[0], o[1], o[2], o[3]);
}

// ---------------- CSR build: block-aggregated bucket sort ----------------
__global__ __launch_bounds__(256) void bhist_kernel(const int* __restrict__ ei,
                                                    int* __restrict__ bcnt,
                                                    const int* __restrict__ flags){
    __shared__ int h[NBUCK];
    int tid = threadIdx.x;
    h[tid] = 0; __syncthreads();
    int f64 = flags[1];
    long e0 = (long)blockIdx.x * EPB + tid;
    #pragma unroll
    for (int r = 0; r < 16; r++){
        long e = e0 + r * 256;
        if (e < NE){
            int d = ldidx(ei, NE + e, f64);
            atomicAdd(&h[d / BN], 1);
        }
    }
    __syncthreads();
    atomicAdd(&bcnt[tid], h[tid]);
}

__global__ __launch_bounds__(256) void bscan_kernel(const int* __restrict__ bcnt,
                                                    int* __restrict__ bbase,
                                                    int* __restrict__ bcur){
    __shared__ int sd[NBUCK];
    int tid = threadIdx.x;
    int v = bcnt[tid];
    sd[tid] = v; __syncthreads();
    for (int off = 1; off < 256; off <<= 1){
        int x = sd[tid];
        int y = (tid >= off) ? sd[tid - off] : 0;
        __syncthreads();
        sd[tid] = x + y;
        __syncthreads();
    }
    int excl = sd[tid] - v;
    bbase[tid] = excl;
    bcur[tid] = excl;
    if (tid == 255) bbase[256] = excl + v;   // == NE
}

__global__ __launch_bounds__(256) void bscatter_kernel(const int* __restrict__ ei,
                                                       int* __restrict__ bcur,
                                                       int2* __restrict__ ebuf,
                                                       const int* __restrict__ flags){
    __shared__ int h[NBUCK], lofs[NBUCK], gbase[NBUCK], lcur[NBUCK];
    __shared__ int2 lstage[EPB];
    int tid = threadIdx.x;
    int f64 = flags[1];
    h[tid] = 0; __syncthreads();
    int2 ed[16]; int bk[16];
    long e0 = (long)blockIdx.x * EPB + tid;
    #pragma unroll
    for (int r = 0; r < 16; r++){
        long e = e0 + r * 256;
        if (e < NE){
            int s = ldidx(ei, e, f64);
            int d = ldidx(ei, NE + e, f64);
            ed[r] = make_int2(s, d);
            bk[r] = d / BN;
            atomicAdd(&h[bk[r]], 1);
        } else bk[r] = -1;
    }
    __syncthreads();
    int v = h[tid];
    lofs[tid] = v; __syncthreads();
    for (int off = 1; off < 256; off <<= 1){
        int x = lofs[tid];
        int y = (tid >= off) ? lofs[tid - off] : 0;
        __syncthreads();
        lofs[tid] = x + y;
        __syncthreads();
    }
    int excl = lofs[tid] - v;
    lofs[tid] = excl;
    lcur[tid] = excl;
    if (v > 0) gbase[tid] = atomicAdd(&bcur[tid], v);
    __syncthreads();
    #pragma unroll
    for (int r = 0; r < 16; r++){
        if (bk[r] >= 0){
            int p = atomicAdd(&lcur[bk[r]], 1);
            lstage[p] = ed[r];
        }
    }
    __syncthreads();
    long base = (long)blockIdx.x * EPB;
    int cnt = (NE - base < EPB) ? (int)(NE - base) : EPB;
    for (int j = tid; j < cnt; j += 256){
        int2 e = lstage[j];
        int i = e.y / BN;
        ebuf[gbase[i] + j - lofs[i]] = e;
    }
}

__global__ __launch_bounds__(256) void place_kernel(const int2* __restrict__ ebuf,
                                                    const int* __restrict__ bbase,
                                                    int* __restrict__ row_ptr,
                                                    int* __restrict__ csr){
    __shared__ int nh[BN];
    __shared__ int nofs[256];
    __shared__ int lcur[BN];
    __shared__ int stage[SMAX];
    int k = blockIdx.x, tid = threadIdx.x;
    int n0 = k * BN;
    int seg0 = bbase[k], len = bbase[k + 1] - seg0;
    for (int i = tid; i < BN; i += 256) nh[i] = 0;
    __syncthreads();
    for (int j = tid; j < len; j += 256){
        int2 e = ebuf[seg0 + j];
        atomicAdd(&nh[e.y - n0], 1);
    }
    __syncthreads();
    int v = (tid < BN) ? nh[tid] : 0;
    nofs[tid] = v; __syncthreads();
    for (int off = 1; off < 256; off <<= 1){
        int x = nofs[tid];
        int y = (tid >= off) ? nofs[tid - off] : 0;
        __syncthreads();
        nofs[tid] = x + y;
        __syncthreads();
    }
    int excl = nofs[tid] - v;
    if (tid < BN){
        lcur[tid] = excl;
        int node = n0 + tid;
        if (node < NN) row_ptr[node] = seg0 + excl;
    }
    if (k == NBUCK - 1 && tid == 0) row_ptr[NN] = NE;
    __syncthreads();
    if (len <= SMAX){
        for (int j = tid; j < len; j += 256){
            int2 e = ebuf[seg0 + j];
            int p = atomicAdd(&lcur[e.y - n0], 1);
            stage[p] = e.x;
        }
        __syncthreads();
        for (int j = tid; j < len; j += 256)
            csr[seg0 + j] = stage[j];
    } else {
        for (int j = tid; j < len; j += 256){
            int2 e = ebuf[seg0 + j];
            int p = atomicAdd(&lcur[e.y - n0], 1);
            csr[seg0 + p] = e.x;
        }
    }
}

// ---------------- MFMA GEMM + es/ed + fp8 pack --------------------------
// out = A[NN x K](bf16) @ W[K x 96] via pre-transposed Wt[96 x K](bf16).
// Block: 64 rows x 96 cols, 4 waves; wave w: rows w*16..+15, 6 col-tiles.
// mfma_f32_16x16x32_bf16: A[m=lane&15][k=(lane>>4)*8+j], B[k][n=lane&15],
// D col=lane&15, row=(lane>>4)*4+r.
template<int K, int H>
__global__ __launch_bounds__(256) void gemm_mfma(const unsigned short* __restrict__ A,
                                                 const unsigned short* __restrict__ Wt,
                                                 const void* __restrict__ as_,
                                                 const void* __restrict__ ad_,
                                                 unsigned short* __restrict__ hq16,
                                                 float* __restrict__ es,
                                                 float* __restrict__ ed,
                                                 const int* __restrict__ flags){
    __shared__ union {
        struct { unsigned short xs[64 * 40]; unsigned short wt[96 * 40]; } s;
        float hs[64 * 104];
    } u;
    int tid = threadIdx.x;
    int row0 = blockIdx.x * 64;
    int lane = tid & 63, w = tid >> 6;
    int m = lane & 15, q = lane >> 4;
    float4v acc[6];
    #pragma unroll
    for (int ct = 0; ct < 6; ct++) acc[ct] = (float4v){0.f, 0.f, 0.f, 0.f};

    int sr = tid >> 2, kp = tid & 3;
    int rr = row0 + sr; if (rr >= NN) rr = NN - 1;

    for (int k0 = 0; k0 < K; k0 += 32){
        *(uint4*)(u.s.xs + sr * 40 + kp * 8) =
            *(const uint4*)(A + (size_t)rr * K + k0 + kp * 8);
        for (int i = tid; i < 96 * 4; i += 256){
            int c = i >> 2, kq = i & 3;
            *(uint4*)(u.s.wt + c * 40 + kq * 8) =
                *(const uint4*)(Wt + (size_t)c * K + k0 + kq * 8);
        }
        __syncthreads();
        short8 a = *(const short8*)(u.s.xs + (w * 16 + m) * 40 + q * 8);
        #pragma unroll
        for (int ct = 0; ct < 6; ct++){
            short8 b = *(const short8*)(u.s.wt + (ct * 16 + m) * 40 + q * 8);
            acc[ct] = __builtin_amdgcn_mfma_f32_16x16x32_bf16(a, b, acc[ct], 0, 0, 0);
        }
        __syncthreads();
    }

    // acc -> LDS (row-major, stride 104)
    #pragma unroll
    for (int ct = 0; ct < 6; ct++)
        #pragma unroll
        for (int r = 0; r < 4; r++)
            u.hs[(w * 16 + q * 4 + r) * 104 + ct * 16 + m] = acc[ct][r];
    __syncthreads();

    // epilogue: thread -> row tid>>2, cols (tid&3)*24..+23
    int rl = tid >> 2, part = tid & 3;
    int row = row0 + rl;
    int isbf = flags[0];
    float hv[24];
    #pragma unroll
    for (int jj = 0; jj < 6; jj++)
        *(float4v*)&hv[jj * 4] = *(const float4v*)&u.hs[rl * 104 + part * 24 + jj * 4];

    float pes = 0.f, ped = 0.f;
    #pragma unroll
    for (int i = 0; i < 24; i++){
        int c = part * 24 + i;
        pes += hv[i] * ldflex(as_, c, isbf);
        ped += hv[i] * ldflex(ad_, c, isbf);
    }
    pes += __shfl_xor(pes, 1); ped += __shfl_xor(ped, 1);
    if (H == 1){ pes += __shfl_xor(pes, 2); ped += __shfl_xor(ped, 2); }

    if (row < NN){
        if (part == 0){ es[(long)row * H] = pes; ed[(long)row * H] = ped; }
        if (H == 2 && part == 2){ es[(long)row * H + 1] = pes; ed[(long)row * H + 1] = ped; }
        unsigned short wds[12];
        #pragma unroll
        for (int j = 0; j < 12; j++) wds[j] = pk_fp8(hv[2 * j], hv[2 * j + 1]);
        uint2* dst = (uint2*)hq16 + (long)row * 16 + part * 3;
        #pragma unroll
        for (int j2 = 0; j2 < 3; j2++){
            uint2 v;
            v.x = (unsigned)wds[4 * j2] | ((unsigned)wds[4 * j2 + 1] << 16);
            v.y = (unsigned)wds[4 * j2 + 2] | ((unsigned)wds[4 * j2 + 3] << 16);
            dst[j2] = v;
        }
    }
}

// ---------------- attention: wave per node, fp8 rows, 2 edges/step --------
// output: bf16-packed rows (96ch = 48 dwords of bf16x2)
template<int H>
__global__ __launch_bounds__(256) void attn_kernel(const unsigned int* __restrict__ hq,
                                                   const float* __restrict__ es,
                                                   const float* __restrict__ ed,
                                                   const int* __restrict__ row_ptr,
                                                   const int* __restrict__ csr,
                                                   const void* __restrict__ bias,
                                                   unsigned int* __restrict__ outb,
                                                   const int* __restrict__ flags){
    int lane = threadIdx.x & 63;
    int d = blockIdx.x * 4 + (threadIdx.x >> 6);
    if (d >= NN) return;
    int isbf = flags[0];
    int beg = row_ptr[d], deg = row_ptr[d + 1] - beg;
    float edd0 = ed[(long)d * H];
    float edd1 = (H == 2) ? ed[(long)d * H + 1] : edd0;
    int g = (lane >= 24 && lane < 48) ? 1 : 0;
    int c = lane - g * 24;
    bool head0 = (c < 12);
    int m = lane - 48;

    int s_nxt = 0; float p0_nxt = 0.f, p1_nxt = 0.f;
    if (lane >= 48 && m < deg){
        int sj = csr[beg + m];
        s_nxt = sj;
        p0_nxt = __expf(lrelu(es[(long)sj * H] + edd0));
        if (H == 2) p1_nxt = __expf(lrelu(es[(long)sj * H + 1] + edd1));
    }

    float acc[4] = {0.f, 0.f, 0.f, 0.f};
    float dn0 = 0.f, dn1 = 0.f;
    for (int base = 0; base < deg; base += 16){
        int s_cur = s_nxt; float p0c = p0_nxt, p1c = p1_nxt;
        dn0 += p0c; dn1 += p1c;
        int nb = base + 16;
        s_nxt = 0; p0_nxt = 0.f; p1_nxt = 0.f;
        if (lane >= 48 && nb + m < deg){
            int sj = csr[beg + nb + m];
            s_nxt = sj;
            p0_nxt = __expf(lrelu(es[(long)sj * H] + edd0));
            if (H == 2) p1_nxt = __expf(lrelu(es[(long)sj * H + 1] + edd1));
        }
        unsigned int v[8]; float pv[8];
        #pragma unroll
        for (int jj = 0; jj < 8; jj++){
            int sa = rdlane_i(s_cur, 48 + 2 * jj);
            int sb = rdlane_i(s_cur, 49 + 2 * jj);
            int s = g ? sb : sa;
            float pa0 = rdlane_f(p0c, 48 + 2 * jj);
            float pb0 = rdlane_f(p0c, 49 + 2 * jj);
            float p;
            if (H == 2){
                float pa1 = rdlane_f(p1c, 48 + 2 * jj);
                float pb1 = rdlane_f(p1c, 49 + 2 * jj);
                float pa = head0 ? pa0 : pa1;
                float pb = head0 ? pb0 : pb1;
                p = g ? pb : pa;
            } else {
                p = g ? pb0 : pa0;
            }
            pv[jj] = p;
            v[jj] = (lane < 48) ? hq[(unsigned)s * 32u + (unsigned)c] : 0u;
        }
        #pragma unroll
        for (int jj = 0; jj < 8; jj++){
            float f[4];
            dec_fp8x4(v[jj], f);
            float p = pv[jj];
            acc[0] += p * f[0]; acc[1] += p * f[1];
            acc[2] += p * f[2]; acc[3] += p * f[3];
        }
    }

    for (int off = 1; off < 16; off <<= 1){
        dn0 += __shfl_xor(dn0, off);
        if (H == 2) dn1 += __shfl_xor(dn1, off);
    }
    float dn0_t = rdlane_f(dn0, 48);
    float dn1_t = (H == 2) ? rdlane_f(dn1, 48) : dn0_t;

    float tot[4];
    #pragma unroll
    for (int k = 0; k < 4; k++) tot[k] = acc[k] + __shfl(acc[k], lane + 24);

    if (lane < 24){
        float ps0 = __expf(lrelu(es[(long)d * H] + edd0));
        float ps1 = (H == 2) ? __expf(lrelu(es[(long)d * H + 1] + edd1)) : ps0;
        float ps = head0 ? ps0 : ps1;
        float dn = (head0 ? dn0_t : dn1_t) + ps;
        float f[4];
        dec_fp8x4(hq[(unsigned)d * 32u + (unsigned)c], f);
        float o0 = fmaxf((tot[0] + ps * f[0]) / dn + ldflex(bias, 4 * c + 0, isbf), 0.f);
        float o1 = fmaxf((tot[1] + ps * f[1]) / dn + ldflex(bias, 4 * c + 1, isbf), 0.f);
        float o2 = fmaxf((tot[2] + ps * f[2]) / dn + ldflex(bias, 4 * c + 2, isbf), 0.f);
        float o3 = fmaxf((tot[3] + ps * f[3]) / dn + ldflex(bias, 4 * c + 3, isbf), 0.f);
        uint2 vv;
        vv.x = (unsigned)f2bf(o0) | ((unsigned)f2bf(o1) << 16);
        vv.y = (unsigned)f2bf(o2) | ((unsigned)f2bf(o3) << 16);
        ((uint2*)outb)[(long)d * 24 + c] = vv;
    }
}

// ---------------- pooling (bf16 input rows, 32 nodes/block) ----------------
__global__ __launch_bounds__(64) void pool_kernel(const unsigned int* __restrict__ bufb,
                                                  const int* __restrict__ batch,
                                                  float* __restrict__ pooled,
                                                  int* __restrict__ gcnt,
                                                  const int* __restrict__ flags){
    int f64 = flags[2];
    int n0 = blockIdx.x * 32;
    if (n0 >= NN) return;
    int n1 = n0 + 32; if (n1 > NN) n1 = NN;
    int lane = threadIdx.x;
    if (lane < 48){
        float a0 = 0.f, a1 = 0.f;
        int curg = ldidx(batch, n0, f64);
        for (int nd = n0; nd < n1; nd++){
            int g = ldidx(batch, nd, f64);
            if (g != curg){
                atomicAdd(&pooled[curg * 96 + 2 * lane], a0);
                atomicAdd(&pooled[curg * 96 + 2 * lane + 1], a1);
                a0 = a1 = 0.f; curg = g;
            }
            unsigned v = bufb[(long)nd * 48 + lane];
            a0 += bf2f((unsigned short)v);
            a1 += bf2f((unsigned short)(v >> 16));
        }
        atomicAdd(&pooled[curg * 96 + 2 * lane], a0);
        atomicAdd(&pooled[curg * 96 + 2 * lane + 1], a1);
    } else if (lane == 48){
        int cnt = 0;
        int curg = ldidx(batch, n0, f64);
        for (int nd = n0; nd < n1; nd++){
            int g = ldidx(batch, nd, f64);
            if (g != curg){
                atomicAdd(&gcnt[curg], cnt);
                cnt = 0; curg = g;
            }
            cnt++;
        }
        atomicAdd(&gcnt[curg], cnt);
    }
}

__global__ void final_kernel(const float* __restrict__ pooled, const int* __restrict__ gcnt,
                             const void* __restrict__ Wc, const void* __restrict__ bc,
                             void* __restrict__ outp, const int* __restrict__ flags){
    int isbf = flags[0];
    int g = threadIdx.x;
    if (g >= NG) return;
    float cnt = (float)gcnt[g];
    if (cnt < 1.f) cnt = 1.f;
    float acc = 0.f;
    for (int c = 0; c < 96; c++)
        acc += (pooled[g * 96 + c] / cnt) * ldflex(Wc, c, isbf);
    acc += ldflex(bc, 0, isbf);
    float sg = 1.f / (1.f + __expf(-acc));
    if (isbf) ((unsigned short*)outp)[g] = f2bf(sg);
    else      ((float*)outp)[g] = sg;
}

extern "C" void kernel_launch(void* const* d_in, const int* in_sizes, int n_in,
                              void* d_out, int out_size, void* d_ws, size_t ws_size,
                              hipStream_t stream){
    const void* x     = d_in[0];
    const int* ei     = (const int*)d_in[1];
    const int* batch  = (const int*)d_in[3];
    const void* W[4]  = {d_in[4],  d_in[8],  d_in[12], d_in[16]};
    const void* AS[4] = {d_in[5],  d_in[9],  d_in[13], d_in[17]};
    const void* AD[4] = {d_in[6],  d_in[10], d_in[14], d_in[18]};
    const void* B[4]  = {d_in[7],  d_in[11], d_in[15], d_in[19]};
    const void* Wc    = d_in[20];
    const void* bc    = d_in[21];

    char* p = (char*)d_ws;
    auto alloc = [&](size_t bytes) -> void* {
        void* r = (void*)p;
        p += (bytes + 255) & ~(size_t)255;
        return r;
    };
    int* flags     = (int*)alloc(16);
    unsigned int* hq = (unsigned int*)alloc((size_t)NN * 128);      // fp8 rows, 128B stride
    unsigned int* buf1b = (unsigned int*)alloc((size_t)NN * 96 * 2); // bf16 attn out
    unsigned short* xb = (unsigned short*)alloc((size_t)NN * 128 * 2); // bf16 x
    unsigned short* wt_all = (unsigned short*)alloc((size_t)(96 * 128 + 3 * 96 * 96) * 2);
    float* es      = (float*)alloc((size_t)NN * 2 * 4);
    float* ed      = (float*)alloc((size_t)NN * 2 * 4);
    int* row_ptr   = (int*)alloc((size_t)(NN + 1) * 4);
    int* csr       = (int*)alloc((size_t)NE * 4);
    int2* ebuf     = (int2*)alloc((size_t)NE * 8);
    int* bcnt      = (int*)alloc((size_t)NBUCK * 4);
    int* bbase     = (int*)alloc((size_t)(NBUCK + 1) * 4);
    int* bcur      = (int*)alloc((size_t)NBUCK * 4);
    float* pooled  = (float*)alloc((size_t)NG * 96 * 4);
    int* gcnt      = (int*)alloc((size_t)NG * 4);

    detect_kernel<<<1, 64, 0, stream>>>((const unsigned short*)x, (const unsigned int*)ei,
                                        (const unsigned int*)batch, flags);

    // prep: W transpose->bf16, x->bf16
    wtprep_kernel<<<4, 256, 0, stream>>>(W[0], W[1], W[2], W[3], wt_all, flags);
    xconv_kernel<<<3125, 256, 0, stream>>>(x, xb, flags);

    // CSR build: LDS-aggregated bucket sort
    hipMemsetAsync(bcnt, 0, (size_t)NBUCK * 4, stream);
    bhist_kernel<<<HB, 256, 0, stream>>>(ei, bcnt, flags);
    bscan_kernel<<<1, 256, 0, stream>>>(bcnt, bbase, bcur);
    bscatter_kernel<<<HB, 256, 0, stream>>>(ei, bcur, ebuf, flags);
    place_kernel<<<NBUCK, 256, 0, stream>>>(ebuf, bbase, row_ptr, csr);

    const int GB = (NN + 63) / 64;        // 782
    const int AB = (NN + 3) / 4;          // 12500
    unsigned short* wt1 = wt_all;
    unsigned short* wt2 = wt_all + 96 * 128;
    unsigned short* wt3 = wt2 + 96 * 96;
    unsigned short* wt4 = wt3 + 96 * 96;

    // layer 1 (H=2, K=128)
    gemm_mfma<128, 2><<<GB, 256, 0, stream>>>(xb, wt1, AS[0], AD[0],
                                              (unsigned short*)hq, es, ed, flags);
    attn_kernel<2><<<AB, 256, 0, stream>>>(hq, es, ed, row_ptr, csr, B[0], buf1b, flags);
    // layers 2..4 (H=1, K=96)
    unsigned short* wts[3] = {wt2, wt3, wt4};
    for (int l = 1; l < 4; l++){
        gemm_mfma<96, 1><<<GB, 256, 0, stream>>>((const unsigned short*)buf1b, wts[l - 1],
                                                 AS[l], AD[l],
                                                 (unsigned short*)hq, es, ed, flags);
        attn_kernel<1><<<AB, 256, 0, stream>>>(hq, es, ed, row_ptr, csr, B[l], buf1b, flags);
    }

    hipMemsetAsync(pooled, 0, (size_t)NG * 96 * 4, stream);
    hipMemsetAsync(gcnt, 0, (size_t)NG * 4, stream);
    pool_kernel<<<(NN + 31) / 32, 64, 0, stream>>>(buf1b, batch, pooled, gcnt, flags);
    final_kernel<<<1, 64, 0, stream>>>(pooled, gcnt, Wc, bc, d_out, flags);
}

// Round 11
// 433.709 us; speedup vs baseline: 2.1033x; 1.0383x over previous
//
#include <hip/hip_runtime.h>
#include <hip/hip_bf16.h>

#define NN 50000
#define NE 800000
#define NG 64
#define NBUCK 256
#define BN 196        // nodes per bucket; 256*196 = 50176 >= NN
#define EPB 4096      // edges per binning block
#define HB 196        // ceil(NE/EPB)
#define SMAX 4200     // per-bucket segment capacity (mean 3136, sigma 56)

typedef __attribute__((ext_vector_type(8))) short short8;
typedef __attribute__((ext_vector_type(4))) float float4v;
typedef __attribute__((ext_vector_type(2))) float float2v;

__device__ __forceinline__ float bf2f(unsigned short u){
    unsigned v = ((unsigned)u) << 16; float f; __builtin_memcpy(&f, &v, 4); return f;
}
__device__ __forceinline__ unsigned short f2bf(float f){
    unsigned u; __builtin_memcpy(&u, &f, 4);
    u = (u + 0x7fffu + ((u >> 16) & 1u)) >> 16;
    return (unsigned short)u;
}
__device__ __forceinline__ float lrelu(float v){ return v > 0.f ? v : 0.2f * v; }

__device__ __forceinline__ float ldflex(const void* p, long i, int isbf){
    if (isbf) return bf2f(((const unsigned short*)p)[i]);
    return ((const float*)p)[i];
}
__device__ __forceinline__ int ldidx(const int* p, long i, int is64){
    return p[is64 ? (i << 1) : i];
}

// ---- fp8 e4m3fn (OCP) pack/unpack, HW cvt when available ----
__device__ __forceinline__ unsigned int enc_fp8_1(float f){
    unsigned u; __builtin_memcpy(&u, &f, 4);
    unsigned s = (u >> 24) & 0x80u;
    float a = fabsf(f); a = fminf(a, 448.f);
    float x = a * 0x1p-120f;
    unsigned xu; __builtin_memcpy(&xu, &x, 4);
    unsigned r = (xu + 0x7FFFFu + ((xu >> 20) & 1u)) >> 20;
    if (r > 0x7Eu) r = 0x7Eu;
    return s | r;
}
__device__ __forceinline__ unsigned short pk_fp8(float a, float b){
#if __has_builtin(__builtin_amdgcn_cvt_pk_fp8_f32)
    int r = __builtin_amdgcn_cvt_pk_fp8_f32(a, b, 0, false);
    return (unsigned short)(r & 0xFFFF);
#else
    return (unsigned short)(enc_fp8_1(a) | (enc_fp8_1(b) << 8));
#endif
}
__device__ __forceinline__ float dec_fp8_manual(unsigned int byte){
    unsigned bits = ((byte & 0x80u) << 24) | ((byte & 0x7Fu) << 20);
    float f; __builtin_memcpy(&f, &bits, 4);
    return f * 0x1p120f;
}
__device__ __forceinline__ void dec_fp8x4_pk(unsigned int v, float2v& lo, float2v& hi){
#if __has_builtin(__builtin_amdgcn_cvt_pk_f32_fp8)
    lo = __builtin_amdgcn_cvt_pk_f32_fp8((int)v, false);
    hi = __builtin_amdgcn_cvt_pk_f32_fp8((int)v, true);
#else
    lo[0] = dec_fp8_manual(v & 0xFF);
    lo[1] = dec_fp8_manual((v >> 8) & 0xFF);
    hi[0] = dec_fp8_manual((v >> 16) & 0xFF);
    hi[1] = dec_fp8_manual((v >> 24) & 0xFF);
#endif
}

__device__ __forceinline__ float rdlane_f(float v, int l){
    int i; __builtin_memcpy(&i, &v, 4);
    int r = __builtin_amdgcn_readlane(i, l);
    float f; __builtin_memcpy(&f, &r, 4);
    return f;
}

// ---------------- runtime dtype detection ----------------
__global__ void detect_kernel(const unsigned short* xu, const unsigned int* eiu,
                              const unsigned int* bu, int* flags){
    if (threadIdx.x != 0 || blockIdx.x != 0) return;
    int hit = 0;
    for (int i = 0; i < 128; i++){
        int ex = (xu[2 * i] >> 7) & 0xFF;
        if (ex >= 100 && ex <= 140) hit++;
    }
    flags[0] = (hit >= 64) ? 1 : 0;
    int z = 0;
    for (int i = 0; i < 128; i++) if (eiu[2 * i + 1] == 0) z++;
    flags[1] = (z >= 120) ? 1 : 0;
    z = 0;
    for (int i = 0; i < 128; i++) if (bu[49745 + 2 * i] == 0) z++;
    flags[2] = (z >= 120) ? 1 : 0;
}

// ---------------- weight transpose + bf16 prep ----------------
__global__ __launch_bounds__(256) void wtprep_kernel(const void* W0, const void* W1,
                                                     const void* W2, const void* W3,
                                                     unsigned short* wt_all,
                                                     const int* flags){
    int l = blockIdx.x;
    const void* W = (l == 0) ? W0 : (l == 1) ? W1 : (l == 2) ? W2 : W3;
    int K = (l == 0) ? 128 : 96;
    unsigned short* out = wt_all + ((l == 0) ? 0 : (96 * 128 + (l - 1) * 96 * 96));
    int isbf = flags[0];
    int tot = 96 * K;
    for (int i = threadIdx.x; i < tot; i += 256){
        int c = i / K, k = i - c * K;
        out[i] = f2bf(ldflex(W, (long)k * 96 + c, isbf));
    }
}

// ---------------- x -> bf16 conversion (layer 1 input) ----------------
__global__ __launch_bounds__(256) void xconv_kernel(const void* x, unsigned short* xb,
                                                    const int* flags){
    int isbf = flags[0];
    long i8 = ((long)blockIdx.x * 256 + threadIdx.x) * 8;
    if (i8 >= (long)NN * 128) return;
    unsigned int o[4];
    #pragma unroll
    for (int j = 0; j < 4; j++){
        unsigned short a = f2bf(ldflex(x, i8 + 2 * j, isbf));
        unsigned short b = f2bf(ldflex(x, i8 + 2 * j + 1, isbf));
        o[j] = (unsigned)a | ((unsigned)b << 16);
    }
    *(uint4*)(xb + i8) = make_uint4(o[0], o[1], o[2], o[3]);
}

// ---------------- CSR build: block-aggregated bucket sort ----------------
__global__ __launch_bounds__(256) void bhist_kernel(const int* __restrict__ ei,
                                                    int* __restrict__ bcnt,
                                                    const int* __restrict__ flags){
    __shared__ int h[NBUCK];
    int tid = threadIdx.x;
    h[tid] = 0; __syncthreads();
    int f64 = flags[1];
    long e0 = (long)blockIdx.x * EPB + tid;
    #pragma unroll
    for (int r = 0; r < 16; r++){
        long e = e0 + r * 256;
        if (e < NE){
            int d = ldidx(ei, NE + e, f64);
            atomicAdd(&h[d / BN], 1);
        }
    }
    __syncthreads();
    atomicAdd(&bcnt[tid], h[tid]);
}

__global__ __launch_bounds__(256) void bscan_kernel(const int* __restrict__ bcnt,
                                                    int* __restrict__ bbase,
                                                    int* __restrict__ bcur){
    __shared__ int sd[NBUCK];
    int tid = threadIdx.x;
    int v = bcnt[tid];
    sd[tid] = v; __syncthreads();
    for (int off = 1; off < 256; off <<= 1){
        int x = sd[tid];
        int y = (tid >= off) ? sd[tid - off] : 0;
        __syncthreads();
        sd[tid] = x + y;
        __syncthreads();
    }
    int excl = sd[tid] - v;
    bbase[tid] = excl;
    bcur[tid] = excl;
    if (tid == 255) bbase[256] = excl + v;   // == NE
}

__global__ __launch_bounds__(256) void bscatter_kernel(const int* __restrict__ ei,
                                                       int* __restrict__ bcur,
                                                       int2* __restrict__ ebuf,
                                                       const int* __restrict__ flags){
    __shared__ int h[NBUCK], lofs[NBUCK], gbase[NBUCK], lcur[NBUCK];
    __shared__ int2 lstage[EPB];
    int tid = threadIdx.x;
    int f64 = flags[1];
    h[tid] = 0; __syncthreads();
    int2 ed[16]; int bk[16];
    long e0 = (long)blockIdx.x * EPB + tid;
    #pragma unroll
    for (int r = 0; r < 16; r++){
        long e = e0 + r * 256;
        if (e < NE){
            int s = ldidx(ei, e, f64);
            int d = ldidx(ei, NE + e, f64);
            ed[r] = make_int2(s, d);
            bk[r] = d / BN;
            atomicAdd(&h[bk[r]], 1);
        } else bk[r] = -1;
    }
    __syncthreads();
    int v = h[tid];
    lofs[tid] = v; __syncthreads();
    for (int off = 1; off < 256; off <<= 1){
        int x = lofs[tid];
        int y = (tid >= off) ? lofs[tid - off] : 0;
        __syncthreads();
        lofs[tid] = x + y;
        __syncthreads();
    }
    int excl = lofs[tid] - v;
    lofs[tid] = excl;
    lcur[tid] = excl;
    if (v > 0) gbase[tid] = atomicAdd(&bcur[tid], v);
    __syncthreads();
    #pragma unroll
    for (int r = 0; r < 16; r++){
        if (bk[r] >= 0){
            int p = atomicAdd(&lcur[bk[r]], 1);
            lstage[p] = ed[r];
        }
    }
    __syncthreads();
    long base = (long)blockIdx.x * EPB;
    int cnt = (NE - base < EPB) ? (int)(NE - base) : EPB;
    for (int j = tid; j < cnt; j += 256){
        int2 e = lstage[j];
        int i = e.y / BN;
        ebuf[gbase[i] + j - lofs[i]] = e;
    }
}

// per-bucket: node-level row_ptr + ordered (s,d) csr dump
__global__ __launch_bounds__(256) void place_kernel(const int2* __restrict__ ebuf,
                                                    const int* __restrict__ bbase,
                                                    int* __restrict__ row_ptr,
                                                    int2* __restrict__ csr2){
    __shared__ int nh[BN];
    __shared__ int nofs[256];
    __shared__ int lcur[BN];
    __shared__ int2 stage[SMAX];
    int k = blockIdx.x, tid = threadIdx.x;
    int n0 = k * BN;
    int seg0 = bbase[k], len = bbase[k + 1] - seg0;
    for (int i = tid; i < BN; i += 256) nh[i] = 0;
    __syncthreads();
    for (int j = tid; j < len; j += 256){
        int2 e = ebuf[seg0 + j];
        atomicAdd(&nh[e.y - n0], 1);
    }
    __syncthreads();
    int v = (tid < BN) ? nh[tid] : 0;
    nofs[tid] = v; __syncthreads();
    for (int off = 1; off < 256; off <<= 1){
        int x = nofs[tid];
        int y = (tid >= off) ? nofs[tid - off] : 0;
        __syncthreads();
        nofs[tid] = x + y;
        __syncthreads();
    }
    int excl = nofs[tid] - v;
    if (tid < BN){
        lcur[tid] = excl;
        int node = n0 + tid;
        if (node < NN) row_ptr[node] = seg0 + excl;
    }
    if (k == NBUCK - 1 && tid == 0) row_ptr[NN] = NE;
    __syncthreads();
    if (len <= SMAX){
        for (int j = tid; j < len; j += 256){
            int2 e = ebuf[seg0 + j];
            int p = atomicAdd(&lcur[e.y - n0], 1);
            stage[p] = e;
        }
        __syncthreads();
        for (int j = tid; j < len; j += 256)
            csr2[seg0 + j] = stage[j];
    } else {
        for (int j = tid; j < len; j += 256){
            int2 e = ebuf[seg0 + j];
            int p = atomicAdd(&lcur[e.y - n0], 1);
            csr2[seg0 + p] = e;
        }
    }
}

// ---------------- MFMA GEMM + es/ed/pself + fp8 pack ---------------------
template<int K, int H>
__global__ __launch_bounds__(256) void gemm_mfma(const unsigned short* __restrict__ A,
                                                 const unsigned short* __restrict__ Wt,
                                                 const void* __restrict__ as_,
                                                 const void* __restrict__ ad_,
                                                 unsigned short* __restrict__ hq16,
                                                 float* __restrict__ es,
                                                 float* __restrict__ ed,
                                                 float* __restrict__ pself,
                                                 const int* __restrict__ flags){
    __shared__ union {
        struct { unsigned short xs[64 * 40]; unsigned short wt[96 * 40]; } s;
        float hs[64 * 104];
    } u;
    int tid = threadIdx.x;
    int row0 = blockIdx.x * 64;
    int lane = tid & 63, w = tid >> 6;
    int m = lane & 15, q = lane >> 4;
    float4v acc[6];
    #pragma unroll
    for (int ct = 0; ct < 6; ct++) acc[ct] = (float4v){0.f, 0.f, 0.f, 0.f};

    int sr = tid >> 2, kp = tid & 3;
    int rr = row0 + sr; if (rr >= NN) rr = NN - 1;

    for (int k0 = 0; k0 < K; k0 += 32){
        *(uint4*)(u.s.xs + sr * 40 + kp * 8) =
            *(const uint4*)(A + (size_t)rr * K + k0 + kp * 8);
        for (int i = tid; i < 96 * 4; i += 256){
            int c = i >> 2, kq = i & 3;
            *(uint4*)(u.s.wt + c * 40 + kq * 8) =
                *(const uint4*)(Wt + (size_t)c * K + k0 + kq * 8);
        }
        __syncthreads();
        short8 a = *(const short8*)(u.s.xs + (w * 16 + m) * 40 + q * 8);
        #pragma unroll
        for (int ct = 0; ct < 6; ct++){
            short8 b = *(const short8*)(u.s.wt + (ct * 16 + m) * 40 + q * 8);
            acc[ct] = __builtin_amdgcn_mfma_f32_16x16x32_bf16(a, b, acc[ct], 0, 0, 0);
        }
        __syncthreads();
    }

    #pragma unroll
    for (int ct = 0; ct < 6; ct++)
        #pragma unroll
        for (int r = 0; r < 4; r++)
            u.hs[(w * 16 + q * 4 + r) * 104 + ct * 16 + m] = acc[ct][r];
    __syncthreads();

    int rl = tid >> 2, part = tid & 3;
    int row = row0 + rl;
    int isbf = flags[0];
    float hv[24];
    #pragma unroll
    for (int jj = 0; jj < 6; jj++)
        *(float4v*)&hv[jj * 4] = *(const float4v*)&u.hs[rl * 104 + part * 24 + jj * 4];

    float pes = 0.f, ped = 0.f;
    #pragma unroll
    for (int i = 0; i < 24; i++){
        int c = part * 24 + i;
        pes += hv[i] * ldflex(as_, c, isbf);
        ped += hv[i] * ldflex(ad_, c, isbf);
    }
    pes += __shfl_xor(pes, 1); ped += __shfl_xor(ped, 1);
    if (H == 1){ pes += __shfl_xor(pes, 2); ped += __shfl_xor(ped, 2); }

    if (row < NN){
        if (part == 0){
            es[(long)row * H] = pes; ed[(long)row * H] = ped;
            pself[(long)row * H] = __expf(lrelu(pes + ped));
        }
        if (H == 2 && part == 2){
            es[(long)row * H + 1] = pes; ed[(long)row * H + 1] = ped;
            pself[(long)row * H + 1] = __expf(lrelu(pes + ped));
        }
        unsigned short wds[12];
        #pragma unroll
        for (int j = 0; j < 12; j++) wds[j] = pk_fp8(hv[2 * j], hv[2 * j + 1]);
        uint2* dst = (uint2*)hq16 + (long)row * 16 + part * 3;
        #pragma unroll
        for (int j2 = 0; j2 < 3; j2++){
            uint2 v;
            v.x = (unsigned)wds[4 * j2] | ((unsigned)wds[4 * j2 + 1] << 16);
            v.y = (unsigned)wds[4 * j2 + 2] | ((unsigned)wds[4 * j2 + 3] << 16);
            dst[j2] = v;
        }
    }
}

// ---------------- per-edge exp scores, packed with src ----------------
// H=1: uint2 {s, p}; H=2: uint4 {s, p0, p1, 0}
template<int H>
__global__ __launch_bounds__(256) void pexp_kernel(const float* __restrict__ es,
                                                   const float* __restrict__ ed,
                                                   const int2* __restrict__ csr2,
                                                   void* __restrict__ edata){
    int i = blockIdx.x * 256 + threadIdx.x;
    if (i >= NE) return;
    int2 e = csr2[i];
    if (H == 1){
        float p = __expf(lrelu(es[e.x] + ed[e.y]));
        ((uint2*)edata)[i] = make_uint2((unsigned)e.x, __float_as_uint(p));
    } else {
        float p0 = __expf(lrelu(es[2 * (long)e.x] + ed[2 * (long)e.y]));
        float p1 = __expf(lrelu(es[2 * (long)e.x + 1] + ed[2 * (long)e.y + 1]));
        ((uint4*)edata)[i] = make_uint4((unsigned)e.x, __float_as_uint(p0),
                                        __float_as_uint(p1), 0u);
    }
}

// ---------------- attention: wave per node, fp8 rows, precomputed p -------
template<int H>
__global__ __launch_bounds__(256) void attn_kernel(const unsigned int* __restrict__ hq,
                                                   const void* __restrict__ edata,
                                                   const float* __restrict__ pself,
                                                   const int* __restrict__ row_ptr,
                                                   const void* __restrict__ bias,
                                                   unsigned int* __restrict__ outb,
                                                   const int* __restrict__ flags){
    int lane = threadIdx.x & 63;
    int d = blockIdx.x * 4 + (threadIdx.x >> 6);
    if (d >= NN) return;
    int isbf = flags[0];
    int beg = row_ptr[d], deg = row_ptr[d + 1] - beg;
    int g = (lane >= 24 && lane < 48) ? 1 : 0;
    int c = lane - g * 24;
    bool head0 = (c < 12);
    int m = lane - 48;

    // prefetch batch 0 metadata (lanes 48-63): one packed load
    int s_nxt = 0; float p0_nxt = 0.f, p1_nxt = 0.f;
    if (lane >= 48 && m < deg){
        if (H == 1){
            uint2 e = ((const uint2*)edata)[beg + m];
            s_nxt = (int)e.x; p0_nxt = __uint_as_float(e.y);
        } else {
            uint4 e = ((const uint4*)edata)[beg + m];
            s_nxt = (int)e.x; p0_nxt = __uint_as_float(e.y); p1_nxt = __uint_as_float(e.z);
        }
    }

    float2v acc01 = {0.f, 0.f}, acc23 = {0.f, 0.f};
    float dn0 = 0.f, dn1 = 0.f;
    for (int base = 0; base < deg; base += 16){
        int s_cur = s_nxt; float p0c = p0_nxt, p1c = p1_nxt;
        dn0 += p0c; dn1 += p1c;
        int nb = base + 16;
        s_nxt = 0; p0_nxt = 0.f; p1_nxt = 0.f;
        if (lane >= 48 && nb + m < deg){
            if (H == 1){
                uint2 e = ((const uint2*)edata)[beg + nb + m];
                s_nxt = (int)e.x; p0_nxt = __uint_as_float(e.y);
            } else {
                uint4 e = ((const uint4*)edata)[beg + nb + m];
                s_nxt = (int)e.x; p0_nxt = __uint_as_float(e.y); p1_nxt = __uint_as_float(e.z);
            }
        }
        unsigned int v[8]; float pv[8];
        #pragma unroll
        for (int jj = 0; jj < 8; jj++){
            int idx = 48 + 2 * jj + g;
            int s = __shfl(s_cur, idx);
            float p0 = __shfl(p0c, idx);
            float p;
            if (H == 2){
                float p1 = __shfl(p1c, idx);
                p = head0 ? p0 : p1;
            } else p = p0;
            pv[jj] = p;
            v[jj] = (lane < 48) ? hq[(unsigned)s * 32u + (unsigned)c] : 0u;
        }
        #pragma unroll
        for (int jj = 0; jj < 8; jj++){
            float2v lo, hi;
            dec_fp8x4_pk(v[jj], lo, hi);
            float2v p2 = {pv[jj], pv[jj]};
            acc01 += p2 * lo;
            acc23 += p2 * hi;
        }
    }

    for (int off = 1; off < 16; off <<= 1){
        dn0 += __shfl_xor(dn0, off);
        if (H == 2) dn1 += __shfl_xor(dn1, off);
    }
    float dn0_t = rdlane_f(dn0, 48);
    float dn1_t = (H == 2) ? rdlane_f(dn1, 48) : dn0_t;

    float tot[4] = {acc01[0], acc01[1], acc23[0], acc23[1]};
    #pragma unroll
    for (int k = 0; k < 4; k++) tot[k] += __shfl(tot[k], lane + 24);

    if (lane < 24){
        int head = (H == 2) ? (head0 ? 0 : 1) : 0;
        float ps = pself[(long)d * H + head];
        float dn = (head0 ? dn0_t : dn1_t) + ps;
        if (H == 1) dn = dn0_t + ps;
        float2v lo, hi;
        dec_fp8x4_pk(hq[(unsigned)d * 32u + (unsigned)c], lo, hi);
        float o0 = fmaxf((tot[0] + ps * lo[0]) / dn + ldflex(bias, 4 * c + 0, isbf), 0.f);
        float o1 = fmaxf((tot[1] + ps * lo[1]) / dn + ldflex(bias, 4 * c + 1, isbf), 0.f);
        float o2 = fmaxf((tot[2] + ps * hi[0]) / dn + ldflex(bias, 4 * c + 2, isbf), 0.f);
        float o3 = fmaxf((tot[3] + ps * hi[1]) / dn + ldflex(bias, 4 * c + 3, isbf), 0.f);
        uint2 vv;
        vv.x = (unsigned)f2bf(o0) | ((unsigned)f2bf(o1) << 16);
        vv.y = (unsigned)f2bf(o2) | ((unsigned)f2bf(o3) << 16);
        ((uint2*)outb)[(long)d * 24 + c] = vv;
    }
}

// ---------------- pooling (bf16 input rows, 32 nodes/block) ----------------
__global__ __launch_bounds__(64) void pool_kernel(const unsigned int* __restrict__ bufb,
                                                  const int* __restrict__ batch,
                                                  float* __restrict__ pooled,
                                                  int* __restrict__ gcnt,
                                                  const int* __restrict__ flags){
    int f64 = flags[2];
    int n0 = blockIdx.x * 32;
    if (n0 >= NN) return;
    int n1 = n0 + 32; if (n1 > NN) n1 = NN;
    int lane = threadIdx.x;
    if (lane < 48){
        float a0 = 0.f, a1 = 0.f;
        int curg = ldidx(batch, n0, f64);
        for (int nd = n0; nd < n1; nd++){
            int g = ldidx(batch, nd, f64);
            if (g != curg){
                atomicAdd(&pooled[curg * 96 + 2 * lane], a0);
                atomicAdd(&pooled[curg * 96 + 2 * lane + 1], a1);
                a0 = a1 = 0.f; curg = g;
            }
            unsigned v = bufb[(long)nd * 48 + lane];
            a0 += bf2f((unsigned short)v);
            a1 += bf2f((unsigned short)(v >> 16));
        }
        atomicAdd(&pooled[curg * 96 + 2 * lane], a0);
        atomicAdd(&pooled[curg * 96 + 2 * lane + 1], a1);
    } else if (lane == 48){
        int cnt = 0;
        int curg = ldidx(batch, n0, f64);
        for (int nd = n0; nd < n1; nd++){
            int g = ldidx(batch, nd, f64);
            if (g != curg){
                atomicAdd(&gcnt[curg], cnt);
                cnt = 0; curg = g;
            }
            cnt++;
        }
        atomicAdd(&gcnt[curg], cnt);
    }
}

__global__ void final_kernel(const float* __restrict__ pooled, const int* __restrict__ gcnt,
                             const void* __restrict__ Wc, const void* __restrict__ bc,
                             void* __restrict__ outp, const int* __restrict__ flags){
    int isbf = flags[0];
    int g = threadIdx.x;
    if (g >= NG) return;
    float cnt = (float)gcnt[g];
    if (cnt < 1.f) cnt = 1.f;
    float acc = 0.f;
    for (int c = 0; c < 96; c++)
        acc += (pooled[g * 96 + c] / cnt) * ldflex(Wc, c, isbf);
    acc += ldflex(bc, 0, isbf);
    float sg = 1.f / (1.f + __expf(-acc));
    if (isbf) ((unsigned short*)outp)[g] = f2bf(sg);
    else      ((float*)outp)[g] = sg;
}

extern "C" void kernel_launch(void* const* d_in, const int* in_sizes, int n_in,
                              void* d_out, int out_size, void* d_ws, size_t ws_size,
                              hipStream_t stream){
    const void* x     = d_in[0];
    const int* ei     = (const int*)d_in[1];
    const int* batch  = (const int*)d_in[3];
    const void* W[4]  = {d_in[4],  d_in[8],  d_in[12], d_in[16]};
    const void* AS[4] = {d_in[5],  d_in[9],  d_in[13], d_in[17]};
    const void* AD[4] = {d_in[6],  d_in[10], d_in[14], d_in[18]};
    const void* B[4]  = {d_in[7],  d_in[11], d_in[15], d_in[19]};
    const void* Wc    = d_in[20];
    const void* bc    = d_in[21];

    char* p = (char*)d_ws;
    auto alloc = [&](size_t bytes) -> void* {
        void* r = (void*)p;
        p += (bytes + 255) & ~(size_t)255;
        return r;
    };
    int* flags     = (int*)alloc(16);
    unsigned int* hq = (unsigned int*)alloc((size_t)NN * 128);        // fp8 rows, 128B stride
    unsigned int* buf1b = (unsigned int*)alloc((size_t)NN * 96 * 2);  // bf16 attn out
    // xb (bf16 x, layer-1 input) and edata (per-edge packed scores) overlap:
    // xb is dead after gemm layer-1, edata written by pexp after it. Both 12.8MB.
    void* xb_edata = alloc((size_t)NE * 16);
    unsigned short* xb = (unsigned short*)xb_edata;
    void* edata = xb_edata;
    unsigned short* wt_all = (unsigned short*)alloc((size_t)(96 * 128 + 3 * 96 * 96) * 2);
    float* es      = (float*)alloc((size_t)NN * 2 * 4);
    float* ed      = (float*)alloc((size_t)NN * 2 * 4);
    float* pself   = (float*)alloc((size_t)NN * 2 * 4);
    int* row_ptr   = (int*)alloc((size_t)(NN + 1) * 4);
    int2* csr2     = (int2*)alloc((size_t)NE * 8);
    int2* ebuf     = (int2*)alloc((size_t)NE * 8);
    int* bcnt      = (int*)alloc((size_t)NBUCK * 4);
    int* bbase     = (int*)alloc((size_t)(NBUCK + 1) * 4);
    int* bcur      = (int*)alloc((size_t)NBUCK * 4);
    float* pooled  = (float*)alloc((size_t)NG * 96 * 4);
    int* gcnt      = (int*)alloc((size_t)NG * 4);

    detect_kernel<<<1, 64, 0, stream>>>((const unsigned short*)x, (const unsigned int*)ei,
                                        (const unsigned int*)batch, flags);

    // prep: W transpose->bf16, x->bf16
    wtprep_kernel<<<4, 256, 0, stream>>>(W[0], W[1], W[2], W[3], wt_all, flags);
    xconv_kernel<<<3125, 256, 0, stream>>>(x, xb, flags);

    // CSR build: LDS-aggregated bucket sort
    hipMemsetAsync(bcnt, 0, (size_t)NBUCK * 4, stream);
    bhist_kernel<<<HB, 256, 0, stream>>>(ei, bcnt, flags);
    bscan_kernel<<<1, 256, 0, stream>>>(bcnt, bbase, bcur);
    bscatter_kernel<<<HB, 256, 0, stream>>>(ei, bcur, ebuf, flags);
    place_kernel<<<NBUCK, 256, 0, stream>>>(ebuf, bbase, row_ptr, csr2);

    const int GB = (NN + 63) / 64;        // 782
    const int AB = (NN + 3) / 4;          // 12500
    const int EB = (NE + 255) / 256;      // 3125
    unsigned short* wt1 = wt_all;
    unsigned short* wt2 = wt_all + 96 * 128;
    unsigned short* wt3 = wt2 + 96 * 96;
    unsigned short* wt4 = wt3 + 96 * 96;

    // layer 1 (H=2, K=128)
    gemm_mfma<128, 2><<<GB, 256, 0, stream>>>(xb, wt1, AS[0], AD[0],
                                              (unsigned short*)hq, es, ed, pself, flags);
    pexp_kernel<2><<<EB, 256, 0, stream>>>(es, ed, csr2, edata);
    attn_kernel<2><<<AB, 256, 0, stream>>>(hq, edata, pself, row_ptr, B[0], buf1b, flags);
    // layers 2..4 (H=1, K=96)
    unsigned short* wts[3] = {wt2, wt3, wt4};
    for (int l = 1; l < 4; l++){
        gemm_mfma<96, 1><<<GB, 256, 0, stream>>>((const unsigned short*)buf1b, wts[l - 1],
                                                 AS[l], AD[l],
                                                 (unsigned short*)hq, es, ed, pself, flags);
        pexp_kernel<1><<<EB, 256, 0, stream>>>(es, ed, csr2, edata);
        attn_kernel<1><<<AB, 256, 0, stream>>>(hq, edata, pself, row_ptr, B[l], buf1b, flags);
    }

    hipMemsetAsync(pooled, 0, (size_t)NG * 96 * 4, stream);
    hipMemsetAsync(gcnt, 0, (size_t)NG * 4, stream);
    pool_kernel<<<(NN + 31) / 32, 64, 0, stream>>>(buf1b, batch, pooled, gcnt, flags);
    final_kernel<<<1, 64, 0, stream>>>(pooled, gcnt, Wc, bc, d_out, flags);
}